// Round 16
// baseline (319.524 us; speedup 1.0000x reference)
//
#include <hip/hip_runtime.h>
#include <math.h>

#define BB 8
#define NN 2048
#define LL 2048
#define CC 256
#define KK 16
#define NL 2
#define FF 4

typedef __attribute__((ext_vector_type(8))) short short8v;
typedef __attribute__((ext_vector_type(4))) float f32x4;

__device__ __forceinline__ short f2b(float f) {
    unsigned u = __float_as_uint(f);
    u += 0x7FFFu + ((u >> 16) & 1u);
    return (short)(u >> 16);
}
__device__ __forceinline__ float b2f(short s) {
    return __uint_as_float(((unsigned)(unsigned short)s) << 16);
}
__device__ __forceinline__ float blo(unsigned u) {       // low bf16 of a pair
    return __uint_as_float(u << 16);
}
__device__ __forceinline__ float bhi(unsigned u) {       // high bf16 of a pair
    return __uint_as_float(u & 0xffff0000u);
}

// async global->LDS, 16B/lane. LDS dest must be lane-linear (wave base +
// lane*16); swizzled layouts are achieved by pre-swizzling the global source.
__device__ __forceinline__ void g2l16(const void* g, void* l) {
    __builtin_amdgcn_global_load_lds(
        (const __attribute__((address_space(1))) void*)g,
        (__attribute__((address_space(3))) void*)l, 16, 0, 0);
}

// ---------------------------------------------------------------- init / convert
__global__ __launch_bounds__(256) void init_k(const float* __restrict__ src,
                                              float* __restrict__ dst,
                                              short* __restrict__ dstb) {
    size_t i = ((size_t)blockIdx.x * 256 + threadIdx.x) * 4;
    float4 v = *reinterpret_cast<const float4*>(src + i);
    *reinterpret_cast<float4*>(dst + i) = v;
    short o[4] = {f2b(v.x), f2b(v.y), f2b(v.z), f2b(v.w)};
    *reinterpret_cast<int2*>(dstb + i) = *reinterpret_cast<int2*>(o);
}

__global__ __launch_bounds__(256) void f2b_k(const float* __restrict__ in,
                                             short* __restrict__ out) {
    size_t i = ((size_t)blockIdx.x * 256 + threadIdx.x) * 4;
    float4 v = *reinterpret_cast<const float4*>(in + i);
    short o[4] = {f2b(v.x), f2b(v.y), f2b(v.z), f2b(v.w)};
    *reinterpret_cast<int2*>(out + i) = *reinterpret_cast<int2*>(o);
}

// W [K][N] fp32 -> Wt [N][K] bf16, batched over blockIdx.z
__global__ __launch_bounds__(256) void tconvB_k(const float* __restrict__ W0,
                                                short* __restrict__ Wt0,
                                                int K, int N,
                                                size_t sin, size_t sout) {
    const float* W = W0 + (size_t)blockIdx.z * sin;
    short* Wt = Wt0 + (size_t)blockIdx.z * sout;
    __shared__ float tile[32][33];
    const int n0 = blockIdx.x * 32, k0 = blockIdx.y * 32;
    const int tx = threadIdx.x & 31, ty = threadIdx.x >> 5;
#pragma unroll
    for (int r = 0; r < 32; r += 8)
        tile[ty + r][tx] = W[(size_t)(k0 + ty + r) * N + n0 + tx];
    __syncthreads();
#pragma unroll
    for (int r = 0; r < 32; r += 8)
        Wt[(size_t)(n0 + ty + r) * K + k0 + tx] = f2b(tile[tx][ty + r]);
}

// ---------------------------------------------------------------- knn (ball query, parallel rank-select)
#define QPB 32
#define CAP 48
__global__ __launch_bounds__(256) void knn_k(const float* __restrict__ qxyz,
                                             const float* __restrict__ kvxyz,
                                             int* __restrict__ idx,
                                             float* __restrict__ valid) {
    __shared__ float4 sxyz[LL];                        // 32 KB
    __shared__ unsigned long long cpk[QPB][CAP + 1];   // +1: leaders on distinct banks
    __shared__ int ccnt[QPB];

    const int t   = threadIdx.x;
    const int q   = t >> 3;              // local query 0..31
    const int sub = t & 7;
    const int b   = blockIdx.x >> 6;     // 64 blocks per batch
    const int n   = ((blockIdx.x & 63) << 5) + q;

    const float* kb = kvxyz + (size_t)b * LL * 3;
    for (int p = t; p < LL; p += 256)
        sxyz[p] = make_float4(kb[3 * p], kb[3 * p + 1], kb[3 * p + 2], 0.f);
    if (t < QPB) ccnt[t] = 0;
    __syncthreads();

    const size_t qo = (size_t)(b * NN + n) * 3;
    const float qx = qxyz[qo], qy = qxyz[qo + 1], qz = qxyz[qo + 2];
    const float rad2 = (float)(0.12 * 0.12);

    for (int j = sub; j < LL; j += 32) {
        float4 p0 = sxyz[j];
        float4 p1 = sxyz[j + 8];
        float4 p2 = sxyz[j + 16];
        float4 p3 = sxyz[j + 24];
        float x0 = qx - p0.x, y0 = qy - p0.y, z0 = qz - p0.z;
        float x1 = qx - p1.x, y1 = qy - p1.y, z1 = qz - p1.z;
        float x2 = qx - p2.x, y2 = qy - p2.y, z2 = qz - p2.z;
        float x3 = qx - p3.x, y3 = qy - p3.y, z3 = qz - p3.z;
        float d0 = fmaf(x0, x0, fmaf(y0, y0, z0 * z0));
        float d1 = fmaf(x1, x1, fmaf(y1, y1, z1 * z1));
        float d2 = fmaf(x2, x2, fmaf(y2, y2, z2 * z2));
        float d3 = fmaf(x3, x3, fmaf(y3, y3, z3 * z3));
        if (fminf(fminf(d0, d1), fminf(d2, d3)) <= rad2) {
            if (d0 <= rad2) {
                int s = atomicAdd(&ccnt[q], 1);
                if (s < CAP) cpk[q][s] = ((unsigned long long)__float_as_uint(d0) << 32) | (unsigned)(j);
            }
            if (d1 <= rad2) {
                int s = atomicAdd(&ccnt[q], 1);
                if (s < CAP) cpk[q][s] = ((unsigned long long)__float_as_uint(d1) << 32) | (unsigned)(j + 8);
            }
            if (d2 <= rad2) {
                int s = atomicAdd(&ccnt[q], 1);
                if (s < CAP) cpk[q][s] = ((unsigned long long)__float_as_uint(d2) << 32) | (unsigned)(j + 16);
            }
            if (d3 <= rad2) {
                int s = atomicAdd(&ccnt[q], 1);
                if (s < CAP) cpk[q][s] = ((unsigned long long)__float_as_uint(d3) << 32) | (unsigned)(j + 24);
            }
        }
    }
    __syncthreads();

    // parallel rank-select: rank(v) = #{u < u64 v}; packed keys are distinct,
    // ties in d2 resolve to lower idx (matches top_k). Softmax is permutation-
    // invariant so slot order is free; we emit by rank (deterministic).
    int c = ccnt[q]; if (c > CAP) c = CAP;
    const size_t o = (size_t)(b * NN + n) * KK;
#pragma unroll 1
    for (int j = sub; j < c; j += 8) {
        const unsigned long long v = cpk[q][j];
        int rank = 0;
#pragma unroll 1
        for (int i = 0; i < c; ++i) rank += (cpk[q][i] < v) ? 1 : 0;
        if (rank < KK) {
            idx[o + rank]   = (int)(v & 0xffffffffu);
            valid[o + rank] = 1.0f;
        }
    }
#pragma unroll
    for (int k = sub; k < KK; k += 8)
        if (k >= c) { idx[o + k] = 0; valid[o + k] = 0.0f; }
}

// ---------------------------------------------------------------- bf16 MFMA GEMM body (128x128)
// Used by wcomb only. Single-buffered (measured best at low TLP).
template <int ACT, int OBF>
__device__ __forceinline__ void mm_body(short* As, short* Bs,
                                        const short* __restrict__ A,
                                        const short* __restrict__ Bt,
                                        const float* __restrict__ bias,
                                        void* __restrict__ Cout,
                                        int N, int Kd, int bx, int by) {
    const int t = threadIdx.x;
    const int lane = t & 63;
    const int wv = t >> 6;
    const int wr = wv >> 1, wc = wv & 1;
    const int lrow = lane & 15;
    const int kc = lane >> 4;
    const int row0 = by * 128;
    const int col0 = bx * 128;

    f32x4 acc[4][4];
#pragma unroll
    for (int m = 0; m < 4; ++m)
#pragma unroll
        for (int n = 0; n < 4; ++n) acc[m][n] = f32x4{0.f, 0.f, 0.f, 0.f};

    const int r0 = t >> 2, cch = t & 3;
    const int scch = cch ^ ((r0 >> 1) & 3);   // pre-swizzled source chunk
    const short* Ap0 = A  + (size_t)(row0 + r0) * Kd + scch * 8;
    const short* Ap1 = A  + (size_t)(row0 + r0 + 64) * Kd + scch * 8;
    const short* Bp0 = Bt + (size_t)(col0 + r0) * Kd + scch * 8;
    const short* Bp1 = Bt + (size_t)(col0 + r0 + 64) * Kd + scch * 8;

    for (int k0 = 0; k0 < Kd; k0 += 32) {
        __syncthreads();
        g2l16(Ap0 + k0, As + t * 8);
        g2l16(Ap1 + k0, As + 2048 + t * 8);
        g2l16(Bp0 + k0, Bs + t * 8);
        g2l16(Bp1 + k0, Bs + 2048 + t * 8);
        __syncthreads();
        short8v af[4], bf[4];
#pragma unroll
        for (int m = 0; m < 4; ++m) {
            const int ar = wr * 64 + m * 16 + lrow;
            af[m] = *(const short8v*)(As + ar * 32 + ((kc ^ ((ar >> 1) & 3)) * 8));
        }
#pragma unroll
        for (int n = 0; n < 4; ++n) {
            const int br = wc * 64 + n * 16 + lrow;
            bf[n] = *(const short8v*)(Bs + br * 32 + ((kc ^ ((br >> 1) & 3)) * 8));
        }
#pragma unroll
        for (int m = 0; m < 4; ++m)
#pragma unroll
            for (int n = 0; n < 4; ++n)
                acc[m][n] = __builtin_amdgcn_mfma_f32_16x16x32_bf16(
                    af[m], bf[n], acc[m][n], 0, 0, 0);
    }

    float bcol[4];
#pragma unroll
    for (int n = 0; n < 4; ++n)
        bcol[n] = bias ? bias[col0 + wc * 64 + n * 16 + lrow] : 0.f;

#pragma unroll
    for (int m = 0; m < 4; ++m) {
#pragma unroll
        for (int n = 0; n < 4; ++n) {
            const int col = col0 + wc * 64 + n * 16 + lrow;
#pragma unroll
            for (int r = 0; r < 4; ++r) {
                const int row = row0 + wr * 64 + m * 16 + kc * 4 + r;
                float v = acc[m][n][r] + bcol[n];
                if (ACT == 1) v = 0.5f * v * (1.0f + erff(v * 0.70710678118654752f));
                if (OBF) ((short*)Cout)[(size_t)row * N + col] = f2b(v);
                else     ((float*)Cout)[(size_t)row * N + col] = v;
            }
        }
    }
}

// combined weights, batched: z = (layer<<1)|sel. sel0: WcdT = WatT x Wdst16;
// sel1: Wsv rows [i*512 .. i*512+255] = WatT x Wsrc16.
__global__ __launch_bounds__(256) void wcomb_k(const short* __restrict__ WatT,
                                               const short* __restrict__ Wdst16,
                                               const short* __restrict__ Wsrc16,
                                               short* __restrict__ WcdT,
                                               short* __restrict__ Wsv) {
    __shared__ __align__(16) short As[128 * 32];
    __shared__ __align__(16) short Bs[128 * 32];
    const int z = blockIdx.z, i = z >> 1, sel = z & 1;
    const short* A = WatT + (size_t)i * CC * CC;
    const short* B = (sel ? Wsrc16 : Wdst16) + (size_t)i * CC * CC;
    short* C = sel ? (Wsv + (size_t)i * 2 * CC * CC) : (WcdT + (size_t)i * CC * CC);
    mm_body<0, 1>(As, Bs, A, B, nullptr, C, CC, CC, blockIdx.x, blockIdx.y);
}

// ---------------------------------------------------------------- 128x256-tile GEMM (W1, swv2)
// Doubled N per block: per K-step 128 MFMA vs 24 KB staging (2x arithmetic
// intensity of 128x128) — the W1 GEMM was staging/barrier-bound (MfmaUtil
// 7.5%). Grid (N/256, M/128) = 512 blocks = 2/CU (TLP preserved).
template <int ACT, int OBF>
__global__ __launch_bounds__(256) void mm256_k(const short* __restrict__ A,
                                               const short* __restrict__ Bt,
                                               const float* __restrict__ bias,
                                               void* __restrict__ Cout,
                                               int N, int Kd) {
    __shared__ __align__(16) short As[128 * 32];   // 8 KB
    __shared__ __align__(16) short Bs[256 * 32];   // 16 KB
    const int t = threadIdx.x;
    const int lane = t & 63;
    const int wv = t >> 6;
    const int wr = wv >> 1, wc = wv & 1;           // wave = 64M x 128N
    const int lrow = lane & 15;
    const int kc = lane >> 4;
    const int row0 = blockIdx.y * 128;
    const int col0 = blockIdx.x * 256;

    f32x4 acc[4][8];
#pragma unroll
    for (int m = 0; m < 4; ++m)
#pragma unroll
        for (int n = 0; n < 8; ++n) acc[m][n] = f32x4{0.f, 0.f, 0.f, 0.f};

    const int r0 = t >> 2, cch = t & 3;
    const int scch = cch ^ ((r0 >> 1) & 3);
    const short* ApA = A  + (size_t)(row0 + r0) * Kd + scch * 8;
    const short* ApB = A  + (size_t)(row0 + r0 + 64) * Kd + scch * 8;
    const short* Bp0 = Bt + (size_t)(col0 + r0) * Kd + scch * 8;
    const short* Bp1 = Bt + (size_t)(col0 + r0 + 64) * Kd + scch * 8;
    const short* Bp2 = Bt + (size_t)(col0 + r0 + 128) * Kd + scch * 8;
    const short* Bp3 = Bt + (size_t)(col0 + r0 + 192) * Kd + scch * 8;

    for (int k0 = 0; k0 < Kd; k0 += 32) {
        __syncthreads();
        g2l16(ApA + k0, As + t * 8);
        g2l16(ApB + k0, As + 2048 + t * 8);
        g2l16(Bp0 + k0, Bs + t * 8);
        g2l16(Bp1 + k0, Bs + 2048 + t * 8);
        g2l16(Bp2 + k0, Bs + 4096 + t * 8);
        g2l16(Bp3 + k0, Bs + 6144 + t * 8);
        __syncthreads();
        short8v af[4], bf[8];
#pragma unroll
        for (int m = 0; m < 4; ++m) {
            const int ar = wr * 64 + m * 16 + lrow;
            af[m] = *(const short8v*)(As + ar * 32 + ((kc ^ ((ar >> 1) & 3)) * 8));
        }
#pragma unroll
        for (int n = 0; n < 8; ++n) {
            const int br = wc * 128 + n * 16 + lrow;
            bf[n] = *(const short8v*)(Bs + br * 32 + ((kc ^ ((br >> 1) & 3)) * 8));
        }
#pragma unroll
        for (int m = 0; m < 4; ++m)
#pragma unroll
            for (int n = 0; n < 8; ++n)
                acc[m][n] = __builtin_amdgcn_mfma_f32_16x16x32_bf16(
                    af[m], bf[n], acc[m][n], 0, 0, 0);
    }

    float bcol[8];
#pragma unroll
    for (int n = 0; n < 8; ++n)
        bcol[n] = bias ? bias[col0 + wc * 128 + n * 16 + lrow] : 0.f;

#pragma unroll
    for (int m = 0; m < 4; ++m) {
#pragma unroll
        for (int n = 0; n < 8; ++n) {
            const int col = col0 + wc * 128 + n * 16 + lrow;
#pragma unroll
            for (int r = 0; r < 4; ++r) {
                const int row = row0 + wr * 64 + m * 16 + kc * 4 + r;
                float v = acc[m][n][r] + bcol[n];
                if (ACT == 1) v = 0.5f * v * (1.0f + erff(v * 0.70710678118654752f));
                if (OBF) ((short*)Cout)[(size_t)row * N + col] = f2b(v);
                else     ((float*)Cout)[(size_t)row * N + col] = v;
            }
        }
    }
}

// ---------------------------------------------------------------- 32-row GEMM (dw)
// 32 rows x 256 cols, K=256, grid M/32 = 512 = 2 blocks/CU (old 128x128 dw
// ran at 1 block/CU = zero TLP). Wave = 16 rows x 128 cols.
__global__ __launch_bounds__(256) void mmrow_k(const short* __restrict__ A,
                                               const short* __restrict__ Bt,
                                               short* __restrict__ Cout) {
    __shared__ __align__(16) short As[32 * 32];    // 2 KB
    __shared__ __align__(16) short Bs[256 * 32];   // 16 KB
    const int t = threadIdx.x;
    const int lane = t & 63;
    const int wv = t >> 6;
    const int rg = wv >> 1;          // row group (16 rows)
    const int chl = wv & 1;          // column half (128 cols)
    const int lrow = lane & 15;
    const int kc = lane >> 4;
    const int row0 = blockIdx.x * 32;
    const int Kd = CC;

    f32x4 acc[8];
#pragma unroll
    for (int n = 0; n < 8; ++n) acc[n] = f32x4{0.f, 0.f, 0.f, 0.f};

    const int r0 = t >> 2, cch = t & 3;
    const int scch = cch ^ ((r0 >> 1) & 3);
    const short* Ap  = A  + (size_t)(row0 + (r0 & 31)) * Kd + scch * 8;
    const short* Bq0 = Bt + (size_t)(r0      ) * Kd + scch * 8;
    const short* Bq1 = Bt + (size_t)(r0 +  64) * Kd + scch * 8;
    const short* Bq2 = Bt + (size_t)(r0 + 128) * Kd + scch * 8;
    const short* Bq3 = Bt + (size_t)(r0 + 192) * Kd + scch * 8;

    for (int k0 = 0; k0 < Kd; k0 += 32) {
        __syncthreads();
        if (t < 128) g2l16(Ap + k0, As + t * 8);
        g2l16(Bq0 + k0, Bs + t * 8);
        g2l16(Bq1 + k0, Bs + 2048 + t * 8);
        g2l16(Bq2 + k0, Bs + 4096 + t * 8);
        g2l16(Bq3 + k0, Bs + 6144 + t * 8);
        __syncthreads();
        const int ar = rg * 16 + lrow;
        short8v af = *(const short8v*)(As + ar * 32 + ((kc ^ ((ar >> 1) & 3)) * 8));
#pragma unroll
        for (int n = 0; n < 8; ++n) {
            const int br = chl * 128 + n * 16 + lrow;
            short8v bf = *(const short8v*)(Bs + br * 32 + ((kc ^ ((br >> 1) & 3)) * 8));
            acc[n] = __builtin_amdgcn_mfma_f32_16x16x32_bf16(af, bf, acc[n], 0, 0, 0);
        }
    }

#pragma unroll
    for (int n = 0; n < 8; ++n) {
        const int col = chl * 128 + n * 16 + lrow;
#pragma unroll
        for (int r = 0; r < 4; ++r) {
            const int row = row0 + rg * 16 + kc * 4 + r;
            Cout[(size_t)row * CC + col] = f2b(acc[n][r]);
        }
    }
}

// ---------------------------------------------------------------- W2 + residual + LN2 (fused)
// Tile 32 rows x 256 cols, K=1024, grid 512 = 2 blocks/CU. Wave w: rows
// (w>>1)*16..+15, cols (w&1)*128. LN row stats via tiny LDS bounce.
#define W2BM 32
__global__ __launch_bounds__(256) void w2ln_k(
    const short* __restrict__ A,      // h16 [M][1024]
    const short* __restrict__ Bt,     // W2T layer [256][1024]
    const float* __restrict__ bias,
    const float* __restrict__ ln_g, const float* __restrict__ ln_b,
    float* __restrict__ out, short* __restrict__ outb) {
    __shared__ __align__(16) short As[W2BM * 32];     // 2 KB
    __shared__ __align__(16) short Bs[256 * 32];      // 16 KB
    __shared__ float sstat[4][16][2];                 // per-wave row (sum, sumsq)
    const int t = threadIdx.x;
    const int lane = t & 63;
    const int wv = t >> 6;
    const int rg = wv >> 1;
    const int chl = wv & 1;
    const int lrow = lane & 15;
    const int kc = lane >> 4;
    const int row0 = blockIdx.x * W2BM;
    const int Kd = CC * FF;

    f32x4 acc[8];
#pragma unroll
    for (int n = 0; n < 8; ++n) acc[n] = f32x4{0.f, 0.f, 0.f, 0.f};

    const int r0 = t >> 2, cch = t & 3;
    const int scch = cch ^ ((r0 >> 1) & 3);
    const short* Ap  = A  + (size_t)(row0 + (r0 & 31)) * Kd + scch * 8;
    const short* Bq0 = Bt + (size_t)(r0      ) * Kd + scch * 8;
    const short* Bq1 = Bt + (size_t)(r0 +  64) * Kd + scch * 8;
    const short* Bq2 = Bt + (size_t)(r0 + 128) * Kd + scch * 8;
    const short* Bq3 = Bt + (size_t)(r0 + 192) * Kd + scch * 8;

    for (int k0 = 0; k0 < Kd; k0 += 32) {
        __syncthreads();
        if (t < 128) g2l16(Ap + k0, As + t * 8);
        g2l16(Bq0 + k0, Bs + t * 8);
        g2l16(Bq1 + k0, Bs + 2048 + t * 8);
        g2l16(Bq2 + k0, Bs + 4096 + t * 8);
        g2l16(Bq3 + k0, Bs + 6144 + t * 8);
        __syncthreads();
        const int ar = rg * 16 + lrow;
        short8v af = *(const short8v*)(As + ar * 32 + ((kc ^ ((ar >> 1) & 3)) * 8));
#pragma unroll
        for (int n = 0; n < 8; ++n) {
            const int br = chl * 128 + n * 16 + lrow;
            short8v bf = *(const short8v*)(Bs + br * 32 + ((kc ^ ((br >> 1) & 3)) * 8));
            acc[n] = __builtin_amdgcn_mfma_f32_16x16x32_bf16(af, bf, acc[n], 0, 0, 0);
        }
    }

    // pre-LN value: acc += bias + residual(out)
#pragma unroll
    for (int n = 0; n < 8; ++n) {
        const int col = chl * 128 + n * 16 + lrow;
        const float bc = bias[col];
#pragma unroll
        for (int r = 0; r < 4; ++r) {
            const int row = row0 + rg * 16 + kc * 4 + r;
            acc[n][r] += bc + out[(size_t)row * CC + col];
        }
    }
    float psum[4], psq[4];
#pragma unroll
    for (int r = 0; r < 4; ++r) {
        float s = 0.f, q = 0.f;
#pragma unroll
        for (int n = 0; n < 8; ++n) {
            s += acc[n][r];
            q = fmaf(acc[n][r], acc[n][r], q);
        }
        s += __shfl_xor(s, 1); s += __shfl_xor(s, 2);
        s += __shfl_xor(s, 4); s += __shfl_xor(s, 8);
        q += __shfl_xor(q, 1); q += __shfl_xor(q, 2);
        q += __shfl_xor(q, 4); q += __shfl_xor(q, 8);
        psum[r] = s; psq[r] = q;
    }
    if (lrow == 0) {
#pragma unroll
        for (int r = 0; r < 4; ++r) {
            sstat[wv][kc * 4 + r][0] = psum[r];
            sstat[wv][kc * 4 + r][1] = psq[r];
        }
    }
    __syncthreads();
#pragma unroll
    for (int r = 0; r < 4; ++r) {
        const int lr = kc * 4 + r;
        const float s = psum[r] + sstat[wv ^ 1][lr][0];
        const float q = psq[r]  + sstat[wv ^ 1][lr][1];
        const float mu = s * (1.0f / 256.0f);
        const float rstd = rsqrtf(fmaxf(q * (1.0f / 256.0f) - mu * mu, 0.f) + 1e-5f);
        const int row = row0 + rg * 16 + lr;
#pragma unroll
        for (int n = 0; n < 8; ++n) {
            const int col = chl * 128 + n * 16 + lrow;
            const float y = (acc[n][r] - mu) * rstd * ln_g[col] + ln_b[col];
            out[(size_t)row * CC + col] = y;
            outb[(size_t)row * CC + col] = f2b(y);
        }
    }
}

// ---------------------------------------------------------------- attention + residual + LN1 (fused)
// Block = 4 queries x 256 channels; thread handles a CHANNEL PAIR (u32 gather
// = 2 bf16) for 2 queries. swv2 rows are 1024 bf16 (both layers); pointer is
// pre-offset to this layer's 512-bf16 half (stride 512 u32 per row). Softmax
// without max-subtract (relu logits bounded, shift-invariant). Batch<->XCD
// pinning keeps gathers L2-resident.
#define AQB 4
__global__ __launch_bounds__(256) void attn_ln_k(
    const short* __restrict__ dw, const short* __restrict__ swv,
    const int* __restrict__ idx, const float* __restrict__ valid,
    const float* __restrict__ bat,
    const float* __restrict__ ln_g, const float* __restrict__ ln_b,
    float* __restrict__ out, short* __restrict__ outb) {
    __shared__ int   sidx[AQB * KK];
    __shared__ float sval[AQB * KK];
    __shared__ __align__(16) float sconv[AQB][CC];   // 4 KB
    const int t = threadIdx.x;
    const int b   = blockIdx.x & 7;                  // batch, pinned to XCD
    const int blk = blockIdx.x >> 3;                 // 0..511 within batch
    const int bn0 = b * NN + blk * AQB;
    const size_t boff = (size_t)b * LL;              // batch offset into [B*L]

    if (t < AQB * KK) {
        sidx[t] = idx[(size_t)bn0 * KK + t];
        sval[t] = valid[(size_t)bn0 * KK + t];
    }
    __syncthreads();

    const int cp = (t & 127) * 2;                    // channel-pair base
    const int qh = t >> 7;                           // query half: 0 or 1
    const float bias0 = bat[cp], bias1 = bat[cp + 1];
    const unsigned* swvu = (const unsigned*)swv;     // layer-offset; row = 512 u32

#pragma unroll
    for (int qq = 0; qq < 2; ++qq) {
        const int q = qh * 2 + qq;
        const int bn = bn0 + q;
        const unsigned du = *(const unsigned*)(dw + (size_t)bn * CC + cp);
        const float d0 = blo(du) + bias0;
        const float d1 = bhi(du) + bias1;
        float s0 = 0.f, s1 = 0.f, n0 = 0.f, n1 = 0.f;
#pragma unroll
        for (int k = 0; k < KK; ++k) {
            const int j = sidx[q * KK + k];
            const float vv = sval[q * KK + k];
            const unsigned* rp = swvu + (boff + j) * 512;
            const unsigned su = rp[cp >> 1];
            const unsigned vu = rp[128 + (cp >> 1)];
            const float e0 = vv * __expf(fmaxf(d0 - blo(su), 0.f));
            const float e1 = vv * __expf(fmaxf(d1 - bhi(su), 0.f));
            s0 += e0; s1 += e1;
            n0 = fmaf(e0, blo(vu), n0);
            n1 = fmaf(e1, bhi(vu), n1);
        }
        sconv[q][cp]     = (s0 > 0.f) ? n0 / s0 : 0.f;
        sconv[q][cp + 1] = (s1 > 0.f) ? n1 / s1 : 0.f;
    }
    __syncthreads();

    const int lane = t & 63, w = t >> 6;
    float4 gg = *reinterpret_cast<const float4*>(&ln_g[lane * 4]);
    float4 bb = *reinterpret_cast<const float4*>(&ln_b[lane * 4]);
    {
        const int q = w;                             // one query per wave
        const size_t base = (size_t)(bn0 + q) * CC + lane * 4;
        float4 x = *reinterpret_cast<const float4*>(&out[base]);
        float4 d = *reinterpret_cast<const float4*>(&sconv[q][lane * 4]);
        float v0 = x.x + d.x, v1 = x.y + d.y, v2 = x.z + d.z, v3 = x.w + d.w;
        float s = v0 + v1 + v2 + v3;
#pragma unroll
        for (int o = 32; o > 0; o >>= 1) s += __shfl_xor(s, o);
        const float mu = s * (1.0f / 256.0f);
        const float t0 = v0 - mu, t1 = v1 - mu, t2 = v2 - mu, t3 = v3 - mu;
        float qv = t0 * t0 + t1 * t1 + t2 * t2 + t3 * t3;
#pragma unroll
        for (int o = 32; o > 0; o >>= 1) qv += __shfl_xor(qv, o);
        const float rstd = rsqrtf(qv * (1.0f / 256.0f) + 1e-5f);
        float4 y;
        y.x = t0 * rstd * gg.x + bb.x;
        y.y = t1 * rstd * gg.y + bb.y;
        y.z = t2 * rstd * gg.z + bb.z;
        y.w = t3 * rstd * gg.w + bb.w;
        *reinterpret_cast<float4*>(&out[base]) = y;
        short o4[4] = {f2b(y.x), f2b(y.y), f2b(y.z), f2b(y.w)};
        *reinterpret_cast<int2*>(outb + base) = *reinterpret_cast<int2*>(o4);
    }
}

// ---------------------------------------------------------------- launch
extern "C" void kernel_launch(void* const* d_in, const int* in_sizes, int n_in,
                              void* d_out, int out_size, void* d_ws, size_t ws_size,
                              hipStream_t stream) {
    const float* q_xyz   = (const float*)d_in[0];
    const float* q_feat  = (const float*)d_in[1];
    const float* kv_xyz  = (const float*)d_in[2];
    const float* kv_feat = (const float*)d_in[3];
    const float* W_src   = (const float*)d_in[4];
    const float* W_dst   = (const float*)d_in[5];
    const float* W_lin   = (const float*)d_in[6];
    const float* W_attn  = (const float*)d_in[7];
    const float* b_attn  = (const float*)d_in[8];
    const float* W1      = (const float*)d_in[9];
    const float* b1      = (const float*)d_in[10];
    const float* W2      = (const float*)d_in[11];
    const float* b2      = (const float*)d_in[12];
    const float* ln1_g   = (const float*)d_in[13];
    const float* ln1_b   = (const float*)d_in[14];
    const float* ln2_g   = (const float*)d_in[15];
    const float* ln2_b   = (const float*)d_in[16];

    float* out = (float*)d_out;
    char* wsb = (char*)d_ws;
    const size_t MB = (size_t)1 << 20;
    int*   idxb   = (int*)(wsb);                 // 1 MB
    float* validb = (float*)(wsb + 1 * MB);      // 1 MB
    short* kvf16  = (short*)(wsb + 2 * MB);      // 8 MB
    short* outb16 = (short*)(wsb + 10 * MB);     // 8 MB
    short* dw16   = (short*)(wsb + 18 * MB);     // 8 MB
    short* swv2   = (short*)(wsb + 26 * MB);     // 32 MB  [M][1024] (l0 sw|v, l1 sw|v)
    short* h16    = (short*)(wsb + 58 * MB);     // 32 MB
    short* WatT   = (short*)(wsb + 90 * MB);                  // 256 KB
    short* Wdst16 = (short*)(wsb + 90 * MB + 256 * 1024);     // 256 KB
    short* Wsrc16 = (short*)(wsb + 90 * MB + 512 * 1024);     // 256 KB
    short* WcdT   = (short*)(wsb + 90 * MB + 768 * 1024);     // 256 KB
    short* Wsv    = (short*)(wsb + 91 * MB);     // 512 KB  [NL][512][256]
    short* W1T    = (short*)(wsb + 92 * MB);     // 1 MB
    short* W2T    = (short*)(wsb + 93 * MB);     // 1 MB

    const int M = BB * NN;                       // 16384

    init_k<<<M * CC / (256 * 4), 256, 0, stream>>>(q_feat, out, outb16);
    f2b_k<<<M * CC / (256 * 4), 256, 0, stream>>>(kv_feat, kvf16);
    f2b_k<<<NL * CC * CC / (256 * 4), 256, 0, stream>>>(W_dst, Wdst16);
    f2b_k<<<NL * CC * CC / (256 * 4), 256, 0, stream>>>(W_src, Wsrc16);
    knn_k<<<BB * (NN / QPB), 256, 0, stream>>>(q_xyz, kv_xyz, idxb, validb);

    // weight prep (batched over z)
    tconvB_k<<<dim3(8, 8, NL), 256, 0, stream>>>(W_attn, WatT, CC, CC,
                                                 (size_t)CC * CC, (size_t)CC * CC);
    tconvB_k<<<dim3(8, 8, NL), 256, 0, stream>>>(W_lin, Wsv + CC * CC, CC, CC,
                                                 (size_t)CC * CC, (size_t)2 * CC * CC);
    tconvB_k<<<dim3(32, 8, NL), 256, 0, stream>>>(W1, W1T, CC, CC * FF,
                                                  (size_t)CC * CC * FF, (size_t)CC * CC * FF);
    tconvB_k<<<dim3(8, 32, NL), 256, 0, stream>>>(W2, W2T, CC * FF, CC,
                                                  (size_t)CC * CC * FF, (size_t)CC * CC * FF);
    wcomb_k<<<dim3(2, 2, 2 * NL), 256, 0, stream>>>(WatT, Wdst16, Wsrc16, WcdT, Wsv);

    // both layers' sw|v in one GEMM: [M][1024] = kvf16 x Wsv^T
    mm256_k<0, 1><<<dim3(4, 128), 256, 0, stream>>>(kvf16, Wsv, nullptr, swv2,
                                                    4 * CC, CC);

    for (int i = 0; i < NL; ++i) {
        const size_t oF = (size_t)i * CC * CC * FF;
        const size_t oC = (size_t)i * CC * CC;
        const float* bat = b_attn + (size_t)i * CC;
        const float* b1p = b1 + (size_t)i * CC * FF;
        const float* b2p = b2 + (size_t)i * CC;

        mmrow_k<<<M / 32, 256, 0, stream>>>(outb16, WcdT + oC, dw16);

        attn_ln_k<<<M / AQB, 256, 0, stream>>>(dw16, swv2 + (size_t)i * 512,
                                               idxb, validb, bat,
                                               ln1_g + (size_t)i * CC, ln1_b + (size_t)i * CC,
                                               out, outb16);

        mm256_k<1, 1><<<dim3(4, 128), 256, 0, stream>>>(outb16, W1T + oF, b1p, h16,
                                                        CC * FF, CC);
        w2ln_k<<<M / W2BM, 256, 0, stream>>>(h16, W2T + oF, b2p,
                                             ln2_g + (size_t)i * CC, ln2_b + (size_t)i * CC,
                                             out, outb16);
    }
    (void)in_sizes; (void)n_in; (void)out_size; (void)ws_size;
}

// Round 17
// 270.581 us; speedup vs baseline: 1.1809x; 1.1809x over previous
//
#include <hip/hip_runtime.h>
#include <math.h>

#define BB 8
#define NN 2048
#define LL 2048
#define CC 256
#define KK 16
#define NL 2
#define FF 4

typedef __attribute__((ext_vector_type(8))) short short8v;
typedef __attribute__((ext_vector_type(4))) float f32x4;

__device__ __forceinline__ short f2b(float f) {
    unsigned u = __float_as_uint(f);
    u += 0x7FFFu + ((u >> 16) & 1u);
    return (short)(u >> 16);
}
__device__ __forceinline__ float b2f(short s) {
    return __uint_as_float(((unsigned)(unsigned short)s) << 16);
}
__device__ __forceinline__ float blo(unsigned u) {       // low bf16 of a pair
    return __uint_as_float(u << 16);
}
__device__ __forceinline__ float bhi(unsigned u) {       // high bf16 of a pair
    return __uint_as_float(u & 0xffff0000u);
}

// async global->LDS, 16B/lane. LDS dest must be lane-linear (wave base +
// lane*16); swizzled layouts are achieved by pre-swizzling the global source.
__device__ __forceinline__ void g2l16(const void* g, void* l) {
    __builtin_amdgcn_global_load_lds(
        (const __attribute__((address_space(1))) void*)g,
        (__attribute__((address_space(3))) void*)l, 16, 0, 0);
}

// ---------------------------------------------------------------- init / convert
__global__ __launch_bounds__(256) void init_k(const float* __restrict__ src,
                                              float* __restrict__ dst,
                                              short* __restrict__ dstb) {
    size_t i = ((size_t)blockIdx.x * 256 + threadIdx.x) * 4;
    float4 v = *reinterpret_cast<const float4*>(src + i);
    *reinterpret_cast<float4*>(dst + i) = v;
    short o[4] = {f2b(v.x), f2b(v.y), f2b(v.z), f2b(v.w)};
    *reinterpret_cast<int2*>(dstb + i) = *reinterpret_cast<int2*>(o);
}

__global__ __launch_bounds__(256) void f2b_k(const float* __restrict__ in,
                                             short* __restrict__ out) {
    size_t i = ((size_t)blockIdx.x * 256 + threadIdx.x) * 4;
    float4 v = *reinterpret_cast<const float4*>(in + i);
    short o[4] = {f2b(v.x), f2b(v.y), f2b(v.z), f2b(v.w)};
    *reinterpret_cast<int2*>(out + i) = *reinterpret_cast<int2*>(o);
}

// W [K][N] fp32 -> Wt [N][K] bf16, batched over blockIdx.z
__global__ __launch_bounds__(256) void tconvB_k(const float* __restrict__ W0,
                                                short* __restrict__ Wt0,
                                                int K, int N,
                                                size_t sin, size_t sout) {
    const float* W = W0 + (size_t)blockIdx.z * sin;
    short* Wt = Wt0 + (size_t)blockIdx.z * sout;
    __shared__ float tile[32][33];
    const int n0 = blockIdx.x * 32, k0 = blockIdx.y * 32;
    const int tx = threadIdx.x & 31, ty = threadIdx.x >> 5;
#pragma unroll
    for (int r = 0; r < 32; r += 8)
        tile[ty + r][tx] = W[(size_t)(k0 + ty + r) * N + n0 + tx];
    __syncthreads();
#pragma unroll
    for (int r = 0; r < 32; r += 8)
        Wt[(size_t)(n0 + ty + r) * K + k0 + tx] = f2b(tile[tx][ty + r]);
}

// ---------------------------------------------------------------- knn (ball query, parallel rank-select)
#define QPB 32
#define CAP 48
__global__ __launch_bounds__(256) void knn_k(const float* __restrict__ qxyz,
                                             const float* __restrict__ kvxyz,
                                             int* __restrict__ idx,
                                             float* __restrict__ valid) {
    __shared__ float4 sxyz[LL];                        // 32 KB
    __shared__ unsigned long long cpk[QPB][CAP + 1];   // +1: leaders on distinct banks
    __shared__ int ccnt[QPB];

    const int t   = threadIdx.x;
    const int q   = t >> 3;              // local query 0..31
    const int sub = t & 7;
    const int b   = blockIdx.x >> 6;     // 64 blocks per batch
    const int n   = ((blockIdx.x & 63) << 5) + q;

    const float* kb = kvxyz + (size_t)b * LL * 3;
    for (int p = t; p < LL; p += 256)
        sxyz[p] = make_float4(kb[3 * p], kb[3 * p + 1], kb[3 * p + 2], 0.f);
    if (t < QPB) ccnt[t] = 0;
    __syncthreads();

    const size_t qo = (size_t)(b * NN + n) * 3;
    const float qx = qxyz[qo], qy = qxyz[qo + 1], qz = qxyz[qo + 2];
    const float rad2 = (float)(0.12 * 0.12);

    for (int j = sub; j < LL; j += 32) {
        float4 p0 = sxyz[j];
        float4 p1 = sxyz[j + 8];
        float4 p2 = sxyz[j + 16];
        float4 p3 = sxyz[j + 24];
        float x0 = qx - p0.x, y0 = qy - p0.y, z0 = qz - p0.z;
        float x1 = qx - p1.x, y1 = qy - p1.y, z1 = qz - p1.z;
        float x2 = qx - p2.x, y2 = qy - p2.y, z2 = qz - p2.z;
        float x3 = qx - p3.x, y3 = qy - p3.y, z3 = qz - p3.z;
        float d0 = fmaf(x0, x0, fmaf(y0, y0, z0 * z0));
        float d1 = fmaf(x1, x1, fmaf(y1, y1, z1 * z1));
        float d2 = fmaf(x2, x2, fmaf(y2, y2, z2 * z2));
        float d3 = fmaf(x3, x3, fmaf(y3, y3, z3 * z3));
        if (fminf(fminf(d0, d1), fminf(d2, d3)) <= rad2) {
            if (d0 <= rad2) {
                int s = atomicAdd(&ccnt[q], 1);
                if (s < CAP) cpk[q][s] = ((unsigned long long)__float_as_uint(d0) << 32) | (unsigned)(j);
            }
            if (d1 <= rad2) {
                int s = atomicAdd(&ccnt[q], 1);
                if (s < CAP) cpk[q][s] = ((unsigned long long)__float_as_uint(d1) << 32) | (unsigned)(j + 8);
            }
            if (d2 <= rad2) {
                int s = atomicAdd(&ccnt[q], 1);
                if (s < CAP) cpk[q][s] = ((unsigned long long)__float_as_uint(d2) << 32) | (unsigned)(j + 16);
            }
            if (d3 <= rad2) {
                int s = atomicAdd(&ccnt[q], 1);
                if (s < CAP) cpk[q][s] = ((unsigned long long)__float_as_uint(d3) << 32) | (unsigned)(j + 24);
            }
        }
    }
    __syncthreads();

    // parallel rank-select: rank(v) = #{u < u64 v}; packed keys are distinct,
    // ties in d2 resolve to lower idx (matches top_k). Softmax is permutation-
    // invariant so slot order is free; we emit by rank (deterministic).
    int c = ccnt[q]; if (c > CAP) c = CAP;
    const size_t o = (size_t)(b * NN + n) * KK;
#pragma unroll 1
    for (int j = sub; j < c; j += 8) {
        const unsigned long long v = cpk[q][j];
        int rank = 0;
#pragma unroll 1
        for (int i = 0; i < c; ++i) rank += (cpk[q][i] < v) ? 1 : 0;
        if (rank < KK) {
            idx[o + rank]   = (int)(v & 0xffffffffu);
            valid[o + rank] = 1.0f;
        }
    }
#pragma unroll
    for (int k = sub; k < KK; k += 8)
        if (k >= c) { idx[o + k] = 0; valid[o + k] = 0.0f; }
}

// ---------------------------------------------------------------- bf16 MFMA GEMM body (128x128, single-buffer)
// Used by dw (2,128) and wcomb — the low-TLP dispatches where deeper
// pipelines measured WORSE (rounds 12/13).
template <int ACT, int OBF>
__device__ __forceinline__ void mm_body(short* As, short* Bs,
                                        const short* __restrict__ A,
                                        const short* __restrict__ Bt,
                                        const float* __restrict__ bias,
                                        void* __restrict__ Cout,
                                        int N, int Kd, int bx, int by) {
    const int t = threadIdx.x;
    const int lane = t & 63;
    const int wv = t >> 6;
    const int wr = wv >> 1, wc = wv & 1;
    const int lrow = lane & 15;
    const int kc = lane >> 4;
    const int row0 = by * 128;
    const int col0 = bx * 128;

    f32x4 acc[4][4];
#pragma unroll
    for (int m = 0; m < 4; ++m)
#pragma unroll
        for (int n = 0; n < 4; ++n) acc[m][n] = f32x4{0.f, 0.f, 0.f, 0.f};

    const int r0 = t >> 2, cch = t & 3;
    const int scch = cch ^ ((r0 >> 1) & 3);   // pre-swizzled source chunk
    const short* Ap0 = A  + (size_t)(row0 + r0) * Kd + scch * 8;
    const short* Ap1 = A  + (size_t)(row0 + r0 + 64) * Kd + scch * 8;
    const short* Bp0 = Bt + (size_t)(col0 + r0) * Kd + scch * 8;
    const short* Bp1 = Bt + (size_t)(col0 + r0 + 64) * Kd + scch * 8;

    for (int k0 = 0; k0 < Kd; k0 += 32) {
        __syncthreads();
        g2l16(Ap0 + k0, As + t * 8);
        g2l16(Ap1 + k0, As + 2048 + t * 8);
        g2l16(Bp0 + k0, Bs + t * 8);
        g2l16(Bp1 + k0, Bs + 2048 + t * 8);
        __syncthreads();
        short8v af[4], bf[4];
#pragma unroll
        for (int m = 0; m < 4; ++m) {
            const int ar = wr * 64 + m * 16 + lrow;
            af[m] = *(const short8v*)(As + ar * 32 + ((kc ^ ((ar >> 1) & 3)) * 8));
        }
#pragma unroll
        for (int n = 0; n < 4; ++n) {
            const int br = wc * 64 + n * 16 + lrow;
            bf[n] = *(const short8v*)(Bs + br * 32 + ((kc ^ ((br >> 1) & 3)) * 8));
        }
#pragma unroll
        for (int m = 0; m < 4; ++m)
#pragma unroll
            for (int n = 0; n < 4; ++n)
                acc[m][n] = __builtin_amdgcn_mfma_f32_16x16x32_bf16(
                    af[m], bf[n], acc[m][n], 0, 0, 0);
    }

    float bcol[4];
#pragma unroll
    for (int n = 0; n < 4; ++n)
        bcol[n] = bias ? bias[col0 + wc * 64 + n * 16 + lrow] : 0.f;

#pragma unroll
    for (int m = 0; m < 4; ++m) {
#pragma unroll
        for (int n = 0; n < 4; ++n) {
            const int col = col0 + wc * 64 + n * 16 + lrow;
#pragma unroll
            for (int r = 0; r < 4; ++r) {
                const int row = row0 + wr * 64 + m * 16 + kc * 4 + r;
                float v = acc[m][n][r] + bcol[n];
                if (ACT == 1) v = 0.5f * v * (1.0f + erff(v * 0.70710678118654752f));
                if (OBF) ((short*)Cout)[(size_t)row * N + col] = f2b(v);
                else     ((float*)Cout)[(size_t)row * N + col] = v;
            }
        }
    }
}

template <int ACT, int OBF>
__global__ __launch_bounds__(256) void mm_k(const short* __restrict__ A,
                                            const short* __restrict__ Bt,
                                            const float* __restrict__ bias,
                                            void* __restrict__ Cout,
                                            int M, int N, int Kd) {
    __shared__ __align__(16) short As[128 * 32];
    __shared__ __align__(16) short Bs[128 * 32];
    mm_body<ACT, OBF>(As, Bs, A, Bt, bias, Cout, N, Kd, blockIdx.x, blockIdx.y);
    (void)M;
}

// ---------------------------------------------------------------- 128x128 GEMM, LDS double-buffered
// For the 4-blocks/CU dispatches ONLY (swv2, W1): with TLP present, the
// early-issued next-tile loads overlap other blocks' compute (round-12 data:
// dbuf helped the 4/CU mm_k sites, hurt the 1/CU ones).
template <int ACT, int OBF>
__global__ __launch_bounds__(256) void mmdb_k(const short* __restrict__ A,
                                              const short* __restrict__ Bt,
                                              const float* __restrict__ bias,
                                              void* __restrict__ Cout,
                                              int M, int N, int Kd) {
    __shared__ __align__(16) short As[2 * 128 * 32];   // 16 KB
    __shared__ __align__(16) short Bs[2 * 128 * 32];   // 16 KB
    const int t = threadIdx.x;
    const int lane = t & 63;
    const int wv = t >> 6;
    const int wr = wv >> 1, wc = wv & 1;
    const int lrow = lane & 15;
    const int kc = lane >> 4;
    const int row0 = blockIdx.y * 128;
    const int col0 = blockIdx.x * 128;

    f32x4 acc[4][4];
#pragma unroll
    for (int m = 0; m < 4; ++m)
#pragma unroll
        for (int n = 0; n < 4; ++n) acc[m][n] = f32x4{0.f, 0.f, 0.f, 0.f};

    const int r0 = t >> 2, cch = t & 3;
    const int scch = cch ^ ((r0 >> 1) & 3);
    const short* Ap0 = A  + (size_t)(row0 + r0) * Kd + scch * 8;
    const short* Ap1 = A  + (size_t)(row0 + r0 + 64) * Kd + scch * 8;
    const short* Bp0 = Bt + (size_t)(col0 + r0) * Kd + scch * 8;
    const short* Bp1 = Bt + (size_t)(col0 + r0 + 64) * Kd + scch * 8;

    auto STAGE = [&](int buf, int k0) {
        g2l16(Ap0 + k0, As + buf * 4096 + t * 8);
        g2l16(Ap1 + k0, As + buf * 4096 + 2048 + t * 8);
        g2l16(Bp0 + k0, Bs + buf * 4096 + t * 8);
        g2l16(Bp1 + k0, Bs + buf * 4096 + 2048 + t * 8);
    };

    STAGE(0, 0);
    __syncthreads();

    const int nt = Kd >> 5;
    int cur = 0;
    for (int tt = 0; tt < nt; ++tt) {
        if (tt + 1 < nt) STAGE(cur ^ 1, (tt + 1) * 32);
        const short* Ac = As + cur * 4096;
        const short* Bc = Bs + cur * 4096;
        short8v af[4], bf[4];
#pragma unroll
        for (int m = 0; m < 4; ++m) {
            const int ar = wr * 64 + m * 16 + lrow;
            af[m] = *(const short8v*)(Ac + ar * 32 + ((kc ^ ((ar >> 1) & 3)) * 8));
        }
#pragma unroll
        for (int n = 0; n < 4; ++n) {
            const int br = wc * 64 + n * 16 + lrow;
            bf[n] = *(const short8v*)(Bc + br * 32 + ((kc ^ ((br >> 1) & 3)) * 8));
        }
#pragma unroll
        for (int m = 0; m < 4; ++m)
#pragma unroll
            for (int n = 0; n < 4; ++n)
                acc[m][n] = __builtin_amdgcn_mfma_f32_16x16x32_bf16(
                    af[m], bf[n], acc[m][n], 0, 0, 0);
        __syncthreads();
        cur ^= 1;
    }

    float bcol[4];
#pragma unroll
    for (int n = 0; n < 4; ++n)
        bcol[n] = bias ? bias[col0 + wc * 64 + n * 16 + lrow] : 0.f;

#pragma unroll
    for (int m = 0; m < 4; ++m) {
#pragma unroll
        for (int n = 0; n < 4; ++n) {
            const int col = col0 + wc * 64 + n * 16 + lrow;
#pragma unroll
            for (int r = 0; r < 4; ++r) {
                const int row = row0 + wr * 64 + m * 16 + kc * 4 + r;
                float v = acc[m][n][r] + bcol[n];
                if (ACT == 1) v = 0.5f * v * (1.0f + erff(v * 0.70710678118654752f));
                if (OBF) ((short*)Cout)[(size_t)row * N + col] = f2b(v);
                else     ((float*)Cout)[(size_t)row * N + col] = v;
            }
        }
    }
    (void)M;
}

// combined weights, batched: z = (layer<<1)|sel. sel0: WcdT = WatT x Wdst16;
// sel1: Wsv rows [i*512 .. i*512+255] = WatT x Wsrc16.
__global__ __launch_bounds__(256) void wcomb_k(const short* __restrict__ WatT,
                                               const short* __restrict__ Wdst16,
                                               const short* __restrict__ Wsrc16,
                                               short* __restrict__ WcdT,
                                               short* __restrict__ Wsv) {
    __shared__ __align__(16) short As[128 * 32];
    __shared__ __align__(16) short Bs[128 * 32];
    const int z = blockIdx.z, i = z >> 1, sel = z & 1;
    const short* A = WatT + (size_t)i * CC * CC;
    const short* B = (sel ? Wsrc16 : Wdst16) + (size_t)i * CC * CC;
    short* C = sel ? (Wsv + (size_t)i * 2 * CC * CC) : (WcdT + (size_t)i * CC * CC);
    mm_body<0, 1>(As, Bs, A, B, nullptr, C, CC, CC, blockIdx.x, blockIdx.y);
}

// ---------------------------------------------------------------- W2 + residual + LN2 (fused)
// Tile 32 rows x 256 cols, K=1024, grid 512 = 2 blocks/CU. Wave w: rows
// (w>>1)*16..+15, cols (w&1)*128. LN row stats via tiny LDS bounce.
#define W2BM 32
__global__ __launch_bounds__(256) void w2ln_k(
    const short* __restrict__ A,      // h16 [M][1024]
    const short* __restrict__ Bt,     // W2T layer [256][1024]
    const float* __restrict__ bias,
    const float* __restrict__ ln_g, const float* __restrict__ ln_b,
    float* __restrict__ out, short* __restrict__ outb) {
    __shared__ __align__(16) short As[W2BM * 32];     // 2 KB
    __shared__ __align__(16) short Bs[256 * 32];      // 16 KB
    __shared__ float sstat[4][16][2];                 // per-wave row (sum, sumsq)
    const int t = threadIdx.x;
    const int lane = t & 63;
    const int wv = t >> 6;
    const int rg = wv >> 1;
    const int chl = wv & 1;
    const int lrow = lane & 15;
    const int kc = lane >> 4;
    const int row0 = blockIdx.x * W2BM;
    const int Kd = CC * FF;

    f32x4 acc[8];
#pragma unroll
    for (int n = 0; n < 8; ++n) acc[n] = f32x4{0.f, 0.f, 0.f, 0.f};

    const int r0 = t >> 2, cch = t & 3;
    const int scch = cch ^ ((r0 >> 1) & 3);
    const short* Ap  = A  + (size_t)(row0 + (r0 & 31)) * Kd + scch * 8;
    const short* Bq0 = Bt + (size_t)(r0      ) * Kd + scch * 8;
    const short* Bq1 = Bt + (size_t)(r0 +  64) * Kd + scch * 8;
    const short* Bq2 = Bt + (size_t)(r0 + 128) * Kd + scch * 8;
    const short* Bq3 = Bt + (size_t)(r0 + 192) * Kd + scch * 8;

    for (int k0 = 0; k0 < Kd; k0 += 32) {
        __syncthreads();
        if (t < 128) g2l16(Ap + k0, As + t * 8);
        g2l16(Bq0 + k0, Bs + t * 8);
        g2l16(Bq1 + k0, Bs + 2048 + t * 8);
        g2l16(Bq2 + k0, Bs + 4096 + t * 8);
        g2l16(Bq3 + k0, Bs + 6144 + t * 8);
        __syncthreads();
        const int ar = rg * 16 + lrow;
        short8v af = *(const short8v*)(As + ar * 32 + ((kc ^ ((ar >> 1) & 3)) * 8));
#pragma unroll
        for (int n = 0; n < 8; ++n) {
            const int br = chl * 128 + n * 16 + lrow;
            short8v bf = *(const short8v*)(Bs + br * 32 + ((kc ^ ((br >> 1) & 3)) * 8));
            acc[n] = __builtin_amdgcn_mfma_f32_16x16x32_bf16(af, bf, acc[n], 0, 0, 0);
        }
    }

    // pre-LN value: acc += bias + residual(out)
#pragma unroll
    for (int n = 0; n < 8; ++n) {
        const int col = chl * 128 + n * 16 + lrow;
        const float bc = bias[col];
#pragma unroll
        for (int r = 0; r < 4; ++r) {
            const int row = row0 + rg * 16 + kc * 4 + r;
            acc[n][r] += bc + out[(size_t)row * CC + col];
        }
    }
    float psum[4], psq[4];
#pragma unroll
    for (int r = 0; r < 4; ++r) {
        float s = 0.f, q = 0.f;
#pragma unroll
        for (int n = 0; n < 8; ++n) {
            s += acc[n][r];
            q = fmaf(acc[n][r], acc[n][r], q);
        }
        s += __shfl_xor(s, 1); s += __shfl_xor(s, 2);
        s += __shfl_xor(s, 4); s += __shfl_xor(s, 8);
        q += __shfl_xor(q, 1); q += __shfl_xor(q, 2);
        q += __shfl_xor(q, 4); q += __shfl_xor(q, 8);
        psum[r] = s; psq[r] = q;
    }
    if (lrow == 0) {
#pragma unroll
        for (int r = 0; r < 4; ++r) {
            sstat[wv][kc * 4 + r][0] = psum[r];
            sstat[wv][kc * 4 + r][1] = psq[r];
        }
    }
    __syncthreads();
#pragma unroll
    for (int r = 0; r < 4; ++r) {
        const int lr = kc * 4 + r;
        const float s = psum[r] + sstat[wv ^ 1][lr][0];
        const float q = psq[r]  + sstat[wv ^ 1][lr][1];
        const float mu = s * (1.0f / 256.0f);
        const float rstd = rsqrtf(fmaxf(q * (1.0f / 256.0f) - mu * mu, 0.f) + 1e-5f);
        const int row = row0 + rg * 16 + lr;
#pragma unroll
        for (int n = 0; n < 8; ++n) {
            const int col = chl * 128 + n * 16 + lrow;
            const float y = (acc[n][r] - mu) * rstd * ln_g[col] + ln_b[col];
            out[(size_t)row * CC + col] = y;
            outb[(size_t)row * CC + col] = f2b(y);
        }
    }
}

// ---------------------------------------------------------------- attention + residual + LN1 (fused)
// Block = 4 queries x 256 channels; thread handles a CHANNEL PAIR (u32 gather
// = 2 bf16) for 2 queries. swv2 rows are 1024 bf16 (both layers); pointer is
// pre-offset to this layer's 512-bf16 half (stride 512 u32 per row). Softmax
// without max-subtract (relu logits bounded, shift-invariant). Batch<->XCD
// pinning keeps gathers L2-resident.
#define AQB 4
__global__ __launch_bounds__(256) void attn_ln_k(
    const short* __restrict__ dw, const short* __restrict__ swv,
    const int* __restrict__ idx, const float* __restrict__ valid,
    const float* __restrict__ bat,
    const float* __restrict__ ln_g, const float* __restrict__ ln_b,
    float* __restrict__ out, short* __restrict__ outb) {
    __shared__ int   sidx[AQB * KK];
    __shared__ float sval[AQB * KK];
    __shared__ __align__(16) float sconv[AQB][CC];   // 4 KB
    const int t = threadIdx.x;
    const int b   = blockIdx.x & 7;                  // batch, pinned to XCD
    const int blk = blockIdx.x >> 3;                 // 0..511 within batch
    const int bn0 = b * NN + blk * AQB;
    const size_t boff = (size_t)b * LL;              // batch offset into [B*L]

    if (t < AQB * KK) {
        sidx[t] = idx[(size_t)bn0 * KK + t];
        sval[t] = valid[(size_t)bn0 * KK + t];
    }
    __syncthreads();

    const int cp = (t & 127) * 2;                    // channel-pair base
    const int qh = t >> 7;                           // query half: 0 or 1
    const float bias0 = bat[cp], bias1 = bat[cp + 1];
    const unsigned* swvu = (const unsigned*)swv;     // layer-offset; row = 512 u32

#pragma unroll
    for (int qq = 0; qq < 2; ++qq) {
        const int q = qh * 2 + qq;
        const int bn = bn0 + q;
        const unsigned du = *(const unsigned*)(dw + (size_t)bn * CC + cp);
        const float d0 = blo(du) + bias0;
        const float d1 = bhi(du) + bias1;
        float s0 = 0.f, s1 = 0.f, n0 = 0.f, n1 = 0.f;
#pragma unroll
        for (int k = 0; k < KK; ++k) {
            const int j = sidx[q * KK + k];
            const float vv = sval[q * KK + k];
            const unsigned* rp = swvu + (boff + j) * 512;
            const unsigned su = rp[cp >> 1];
            const unsigned vu = rp[128 + (cp >> 1)];
            const float e0 = vv * __expf(fmaxf(d0 - blo(su), 0.f));
            const float e1 = vv * __expf(fmaxf(d1 - bhi(su), 0.f));
            s0 += e0; s1 += e1;
            n0 = fmaf(e0, blo(vu), n0);
            n1 = fmaf(e1, bhi(vu), n1);
        }
        sconv[q][cp]     = (s0 > 0.f) ? n0 / s0 : 0.f;
        sconv[q][cp + 1] = (s1 > 0.f) ? n1 / s1 : 0.f;
    }
    __syncthreads();

    const int lane = t & 63, w = t >> 6;
    float4 gg = *reinterpret_cast<const float4*>(&ln_g[lane * 4]);
    float4 bb = *reinterpret_cast<const float4*>(&ln_b[lane * 4]);
    {
        const int q = w;                             // one query per wave
        const size_t base = (size_t)(bn0 + q) * CC + lane * 4;
        float4 x = *reinterpret_cast<const float4*>(&out[base]);
        float4 d = *reinterpret_cast<const float4*>(&sconv[q][lane * 4]);
        float v0 = x.x + d.x, v1 = x.y + d.y, v2 = x.z + d.z, v3 = x.w + d.w;
        float s = v0 + v1 + v2 + v3;
#pragma unroll
        for (int o = 32; o > 0; o >>= 1) s += __shfl_xor(s, o);
        const float mu = s * (1.0f / 256.0f);
        const float t0 = v0 - mu, t1 = v1 - mu, t2 = v2 - mu, t3 = v3 - mu;
        float qv = t0 * t0 + t1 * t1 + t2 * t2 + t3 * t3;
#pragma unroll
        for (int o = 32; o > 0; o >>= 1) qv += __shfl_xor(qv, o);
        const float rstd = rsqrtf(qv * (1.0f / 256.0f) + 1e-5f);
        float4 y;
        y.x = t0 * rstd * gg.x + bb.x;
        y.y = t1 * rstd * gg.y + bb.y;
        y.z = t2 * rstd * gg.z + bb.z;
        y.w = t3 * rstd * gg.w + bb.w;
        *reinterpret_cast<float4*>(&out[base]) = y;
        short o4[4] = {f2b(y.x), f2b(y.y), f2b(y.z), f2b(y.w)};
        *reinterpret_cast<int2*>(outb + base) = *reinterpret_cast<int2*>(o4);
    }
}

// ---------------------------------------------------------------- launch
extern "C" void kernel_launch(void* const* d_in, const int* in_sizes, int n_in,
                              void* d_out, int out_size, void* d_ws, size_t ws_size,
                              hipStream_t stream) {
    const float* q_xyz   = (const float*)d_in[0];
    const float* q_feat  = (const float*)d_in[1];
    const float* kv_xyz  = (const float*)d_in[2];
    const float* kv_feat = (const float*)d_in[3];
    const float* W_src   = (const float*)d_in[4];
    const float* W_dst   = (const float*)d_in[5];
    const float* W_lin   = (const float*)d_in[6];
    const float* W_attn  = (const float*)d_in[7];
    const float* b_attn  = (const float*)d_in[8];
    const float* W1      = (const float*)d_in[9];
    const float* b1      = (const float*)d_in[10];
    const float* W2      = (const float*)d_in[11];
    const float* b2      = (const float*)d_in[12];
    const float* ln1_g   = (const float*)d_in[13];
    const float* ln1_b   = (const float*)d_in[14];
    const float* ln2_g   = (const float*)d_in[15];
    const float* ln2_b   = (const float*)d_in[16];

    float* out = (float*)d_out;
    char* wsb = (char*)d_ws;
    const size_t MB = (size_t)1 << 20;
    int*   idxb   = (int*)(wsb);                 // 1 MB
    float* validb = (float*)(wsb + 1 * MB);      // 1 MB
    short* kvf16  = (short*)(wsb + 2 * MB);      // 8 MB
    short* outb16 = (short*)(wsb + 10 * MB);     // 8 MB
    short* dw16   = (short*)(wsb + 18 * MB);     // 8 MB
    short* swv2   = (short*)(wsb + 26 * MB);     // 32 MB  [M][1024] (l0 sw|v, l1 sw|v)
    short* h16    = (short*)(wsb + 58 * MB);     // 32 MB
    short* WatT   = (short*)(wsb + 90 * MB);                  // 256 KB
    short* Wdst16 = (short*)(wsb + 90 * MB + 256 * 1024);     // 256 KB
    short* Wsrc16 = (short*)(wsb + 90 * MB + 512 * 1024);     // 256 KB
    short* WcdT   = (short*)(wsb + 90 * MB + 768 * 1024);     // 256 KB
    short* Wsv    = (short*)(wsb + 91 * MB);     // 512 KB  [NL][512][256]
    short* W1T    = (short*)(wsb + 92 * MB);     // 1 MB
    short* W2T    = (short*)(wsb + 93 * MB);     // 1 MB

    const int M = BB * NN;                       // 16384

    init_k<<<M * CC / (256 * 4), 256, 0, stream>>>(q_feat, out, outb16);
    f2b_k<<<M * CC / (256 * 4), 256, 0, stream>>>(kv_feat, kvf16);
    f2b_k<<<NL * CC * CC / (256 * 4), 256, 0, stream>>>(W_dst, Wdst16);
    f2b_k<<<NL * CC * CC / (256 * 4), 256, 0, stream>>>(W_src, Wsrc16);
    knn_k<<<BB * (NN / QPB), 256, 0, stream>>>(q_xyz, kv_xyz, idxb, validb);

    // weight prep (batched over z)
    tconvB_k<<<dim3(8, 8, NL), 256, 0, stream>>>(W_attn, WatT, CC, CC,
                                                 (size_t)CC * CC, (size_t)CC * CC);
    tconvB_k<<<dim3(8, 8, NL), 256, 0, stream>>>(W_lin, Wsv + CC * CC, CC, CC,
                                                 (size_t)CC * CC, (size_t)2 * CC * CC);
    tconvB_k<<<dim3(32, 8, NL), 256, 0, stream>>>(W1, W1T, CC, CC * FF,
                                                  (size_t)CC * CC * FF, (size_t)CC * CC * FF);
    tconvB_k<<<dim3(8, 32, NL), 256, 0, stream>>>(W2, W2T, CC * FF, CC,
                                                  (size_t)CC * CC * FF, (size_t)CC * CC * FF);
    wcomb_k<<<dim3(2, 2, 2 * NL), 256, 0, stream>>>(WatT, Wdst16, Wsrc16, WcdT, Wsv);

    // both layers' sw|v in one GEMM: [M][1024] = kvf16 x Wsv^T (4 blocks/CU)
    mmdb_k<0, 1><<<dim3(8, 128), 256, 0, stream>>>(kvf16, Wsv, nullptr, swv2,
                                                   M, 4 * CC, CC);

    for (int i = 0; i < NL; ++i) {
        const size_t oF = (size_t)i * CC * CC * FF;
        const size_t oC = (size_t)i * CC * CC;
        const float* bat = b_attn + (size_t)i * CC;
        const float* b1p = b1 + (size_t)i * CC * FF;
        const float* b2p = b2 + (size_t)i * CC;

        mm_k<0, 1><<<dim3(2, 128), 256, 0, stream>>>(outb16, WcdT + oC, nullptr, dw16, M, CC, CC);

        attn_ln_k<<<M / AQB, 256, 0, stream>>>(dw16, swv2 + (size_t)i * 512,
                                               idxb, validb, bat,
                                               ln1_g + (size_t)i * CC, ln1_b + (size_t)i * CC,
                                               out, outb16);

        mmdb_k<1, 1><<<dim3(8, 128), 256, 0, stream>>>(outb16, W1T + oF, b1p, h16,
                                                       M, CC * FF, CC);
        w2ln_k<<<M / W2BM, 256, 0, stream>>>(h16, W2T + oF, b2p,
                                             ln2_g + (size_t)i * CC, ln2_b + (size_t)i * CC,
                                             out, outb16);
    }
    (void)in_sizes; (void)n_in; (void)out_size; (void)ws_size;
}

// Round 18
// 266.864 us; speedup vs baseline: 1.1973x; 1.0139x over previous
//
#include <hip/hip_runtime.h>
#include <math.h>

#define BB 8
#define NN 2048
#define LL 2048
#define CC 256
#define KK 16
#define NL 2
#define FF 4

typedef __attribute__((ext_vector_type(8))) short short8v;
typedef __attribute__((ext_vector_type(4))) float f32x4;

__device__ __forceinline__ short f2b(float f) {
    unsigned u = __float_as_uint(f);
    u += 0x7FFFu + ((u >> 16) & 1u);
    return (short)(u >> 16);
}
__device__ __forceinline__ float b2f(short s) {
    return __uint_as_float(((unsigned)(unsigned short)s) << 16);
}
__device__ __forceinline__ float blo(unsigned u) {       // low bf16 of a pair
    return __uint_as_float(u << 16);
}
__device__ __forceinline__ float bhi(unsigned u) {       // high bf16 of a pair
    return __uint_as_float(u & 0xffff0000u);
}

// async global->LDS, 16B/lane. LDS dest must be lane-linear (wave base +
// lane*16); swizzled layouts are achieved by pre-swizzling the global source.
__device__ __forceinline__ void g2l16(const void* g, void* l) {
    __builtin_amdgcn_global_load_lds(
        (const __attribute__((address_space(1))) void*)g,
        (__attribute__((address_space(3))) void*)l, 16, 0, 0);
}

// ---------------------------------------------------------------- init / convert
__global__ __launch_bounds__(256) void init_k(const float* __restrict__ src,
                                              float* __restrict__ dst,
                                              short* __restrict__ dstb) {
    size_t i = ((size_t)blockIdx.x * 256 + threadIdx.x) * 4;
    float4 v = *reinterpret_cast<const float4*>(src + i);
    *reinterpret_cast<float4*>(dst + i) = v;
    short o[4] = {f2b(v.x), f2b(v.y), f2b(v.z), f2b(v.w)};
    *reinterpret_cast<int2*>(dstb + i) = *reinterpret_cast<int2*>(o);
}

__global__ __launch_bounds__(256) void f2b_k(const float* __restrict__ in,
                                             short* __restrict__ out) {
    size_t i = ((size_t)blockIdx.x * 256 + threadIdx.x) * 4;
    float4 v = *reinterpret_cast<const float4*>(in + i);
    short o[4] = {f2b(v.x), f2b(v.y), f2b(v.z), f2b(v.w)};
    *reinterpret_cast<int2*>(out + i) = *reinterpret_cast<int2*>(o);
}

// W [K][N] fp32 -> Wt [N][K] bf16, batched over blockIdx.z
__global__ __launch_bounds__(256) void tconvB_k(const float* __restrict__ W0,
                                                short* __restrict__ Wt0,
                                                int K, int N,
                                                size_t sin, size_t sout) {
    const float* W = W0 + (size_t)blockIdx.z * sin;
    short* Wt = Wt0 + (size_t)blockIdx.z * sout;
    __shared__ float tile[32][33];
    const int n0 = blockIdx.x * 32, k0 = blockIdx.y * 32;
    const int tx = threadIdx.x & 31, ty = threadIdx.x >> 5;
#pragma unroll
    for (int r = 0; r < 32; r += 8)
        tile[ty + r][tx] = W[(size_t)(k0 + ty + r) * N + n0 + tx];
    __syncthreads();
#pragma unroll
    for (int r = 0; r < 32; r += 8)
        Wt[(size_t)(n0 + ty + r) * K + k0 + tx] = f2b(tile[tx][ty + r]);
}

// ---------------------------------------------------------------- knn (ball query, parallel rank-select)
#define QPB 32
#define CAP 48
__global__ __launch_bounds__(256) void knn_k(const float* __restrict__ qxyz,
                                             const float* __restrict__ kvxyz,
                                             int* __restrict__ idx,
                                             float* __restrict__ valid) {
    __shared__ float4 sxyz[LL];                        // 32 KB
    __shared__ unsigned long long cpk[QPB][CAP + 1];   // +1: leaders on distinct banks
    __shared__ int ccnt[QPB];

    const int t   = threadIdx.x;
    const int q   = t >> 3;              // local query 0..31
    const int sub = t & 7;
    const int b   = blockIdx.x >> 6;     // 64 blocks per batch
    const int n   = ((blockIdx.x & 63) << 5) + q;

    const float* kb = kvxyz + (size_t)b * LL * 3;
    for (int p = t; p < LL; p += 256)
        sxyz[p] = make_float4(kb[3 * p], kb[3 * p + 1], kb[3 * p + 2], 0.f);
    if (t < QPB) ccnt[t] = 0;
    __syncthreads();

    const size_t qo = (size_t)(b * NN + n) * 3;
    const float qx = qxyz[qo], qy = qxyz[qo + 1], qz = qxyz[qo + 2];
    const float rad2 = (float)(0.12 * 0.12);

    for (int j = sub; j < LL; j += 32) {
        float4 p0 = sxyz[j];
        float4 p1 = sxyz[j + 8];
        float4 p2 = sxyz[j + 16];
        float4 p3 = sxyz[j + 24];
        float x0 = qx - p0.x, y0 = qy - p0.y, z0 = qz - p0.z;
        float x1 = qx - p1.x, y1 = qy - p1.y, z1 = qz - p1.z;
        float x2 = qx - p2.x, y2 = qy - p2.y, z2 = qz - p2.z;
        float x3 = qx - p3.x, y3 = qy - p3.y, z3 = qz - p3.z;
        float d0 = fmaf(x0, x0, fmaf(y0, y0, z0 * z0));
        float d1 = fmaf(x1, x1, fmaf(y1, y1, z1 * z1));
        float d2 = fmaf(x2, x2, fmaf(y2, y2, z2 * z2));
        float d3 = fmaf(x3, x3, fmaf(y3, y3, z3 * z3));
        if (fminf(fminf(d0, d1), fminf(d2, d3)) <= rad2) {
            if (d0 <= rad2) {
                int s = atomicAdd(&ccnt[q], 1);
                if (s < CAP) cpk[q][s] = ((unsigned long long)__float_as_uint(d0) << 32) | (unsigned)(j);
            }
            if (d1 <= rad2) {
                int s = atomicAdd(&ccnt[q], 1);
                if (s < CAP) cpk[q][s] = ((unsigned long long)__float_as_uint(d1) << 32) | (unsigned)(j + 8);
            }
            if (d2 <= rad2) {
                int s = atomicAdd(&ccnt[q], 1);
                if (s < CAP) cpk[q][s] = ((unsigned long long)__float_as_uint(d2) << 32) | (unsigned)(j + 16);
            }
            if (d3 <= rad2) {
                int s = atomicAdd(&ccnt[q], 1);
                if (s < CAP) cpk[q][s] = ((unsigned long long)__float_as_uint(d3) << 32) | (unsigned)(j + 24);
            }
        }
    }
    __syncthreads();

    // parallel rank-select: rank(v) = #{u < u64 v}; packed keys are distinct,
    // ties in d2 resolve to lower idx (matches top_k). Softmax is permutation-
    // invariant so slot order is free; we emit by rank (deterministic).
    int c = ccnt[q]; if (c > CAP) c = CAP;
    const size_t o = (size_t)(b * NN + n) * KK;
#pragma unroll 1
    for (int j = sub; j < c; j += 8) {
        const unsigned long long v = cpk[q][j];
        int rank = 0;
#pragma unroll 1
        for (int i = 0; i < c; ++i) rank += (cpk[q][i] < v) ? 1 : 0;
        if (rank < KK) {
            idx[o + rank]   = (int)(v & 0xffffffffu);
            valid[o + rank] = 1.0f;
        }
    }
#pragma unroll
    for (int k = sub; k < KK; k += 8)
        if (k >= c) { idx[o + k] = 0; valid[o + k] = 0.0f; }
}

// ---------------------------------------------------------------- bf16 MFMA GEMM body (128x128, single-buffer)
// Used by wcomb — low-TLP weight prep.
template <int ACT, int OBF>
__device__ __forceinline__ void mm_body(short* As, short* Bs,
                                        const short* __restrict__ A,
                                        const short* __restrict__ Bt,
                                        const float* __restrict__ bias,
                                        void* __restrict__ Cout,
                                        int N, int Kd, int bx, int by) {
    const int t = threadIdx.x;
    const int lane = t & 63;
    const int wv = t >> 6;
    const int wr = wv >> 1, wc = wv & 1;
    const int lrow = lane & 15;
    const int kc = lane >> 4;
    const int row0 = by * 128;
    const int col0 = bx * 128;

    f32x4 acc[4][4];
#pragma unroll
    for (int m = 0; m < 4; ++m)
#pragma unroll
        for (int n = 0; n < 4; ++n) acc[m][n] = f32x4{0.f, 0.f, 0.f, 0.f};

    const int r0 = t >> 2, cch = t & 3;
    const int scch = cch ^ ((r0 >> 1) & 3);   // pre-swizzled source chunk
    const short* Ap0 = A  + (size_t)(row0 + r0) * Kd + scch * 8;
    const short* Ap1 = A  + (size_t)(row0 + r0 + 64) * Kd + scch * 8;
    const short* Bp0 = Bt + (size_t)(col0 + r0) * Kd + scch * 8;
    const short* Bp1 = Bt + (size_t)(col0 + r0 + 64) * Kd + scch * 8;

    for (int k0 = 0; k0 < Kd; k0 += 32) {
        __syncthreads();
        g2l16(Ap0 + k0, As + t * 8);
        g2l16(Ap1 + k0, As + 2048 + t * 8);
        g2l16(Bp0 + k0, Bs + t * 8);
        g2l16(Bp1 + k0, Bs + 2048 + t * 8);
        __syncthreads();
        short8v af[4], bf[4];
#pragma unroll
        for (int m = 0; m < 4; ++m) {
            const int ar = wr * 64 + m * 16 + lrow;
            af[m] = *(const short8v*)(As + ar * 32 + ((kc ^ ((ar >> 1) & 3)) * 8));
        }
#pragma unroll
        for (int n = 0; n < 4; ++n) {
            const int br = wc * 64 + n * 16 + lrow;
            bf[n] = *(const short8v*)(Bs + br * 32 + ((kc ^ ((br >> 1) & 3)) * 8));
        }
#pragma unroll
        for (int m = 0; m < 4; ++m)
#pragma unroll
            for (int n = 0; n < 4; ++n)
                acc[m][n] = __builtin_amdgcn_mfma_f32_16x16x32_bf16(
                    af[m], bf[n], acc[m][n], 0, 0, 0);
    }

    float bcol[4];
#pragma unroll
    for (int n = 0; n < 4; ++n)
        bcol[n] = bias ? bias[col0 + wc * 64 + n * 16 + lrow] : 0.f;

#pragma unroll
    for (int m = 0; m < 4; ++m) {
#pragma unroll
        for (int n = 0; n < 4; ++n) {
            const int col = col0 + wc * 64 + n * 16 + lrow;
#pragma unroll
            for (int r = 0; r < 4; ++r) {
                const int row = row0 + wr * 64 + m * 16 + kc * 4 + r;
                float v = acc[m][n][r] + bcol[n];
                if (ACT == 1) v = 0.5f * v * (1.0f + erff(v * 0.70710678118654752f));
                if (OBF) ((short*)Cout)[(size_t)row * N + col] = f2b(v);
                else     ((float*)Cout)[(size_t)row * N + col] = v;
            }
        }
    }
}

// ---------------------------------------------------------------- 128x128 GEMM, LDS double-buffered
// For the 4-blocks/CU dispatches (swv2, W1): with TLP present, early-issued
// next-tile loads overlap other blocks' compute (round-17: confirmed win).
template <int ACT, int OBF>
__global__ __launch_bounds__(256) void mmdb_k(const short* __restrict__ A,
                                              const short* __restrict__ Bt,
                                              const float* __restrict__ bias,
                                              void* __restrict__ Cout,
                                              int M, int N, int Kd) {
    __shared__ __align__(16) short As[2 * 128 * 32];   // 16 KB
    __shared__ __align__(16) short Bs[2 * 128 * 32];   // 16 KB
    const int t = threadIdx.x;
    const int lane = t & 63;
    const int wv = t >> 6;
    const int wr = wv >> 1, wc = wv & 1;
    const int lrow = lane & 15;
    const int kc = lane >> 4;
    const int row0 = blockIdx.y * 128;
    const int col0 = blockIdx.x * 128;

    f32x4 acc[4][4];
#pragma unroll
    for (int m = 0; m < 4; ++m)
#pragma unroll
        for (int n = 0; n < 4; ++n) acc[m][n] = f32x4{0.f, 0.f, 0.f, 0.f};

    const int r0 = t >> 2, cch = t & 3;
    const int scch = cch ^ ((r0 >> 1) & 3);
    const short* Ap0 = A  + (size_t)(row0 + r0) * Kd + scch * 8;
    const short* Ap1 = A  + (size_t)(row0 + r0 + 64) * Kd + scch * 8;
    const short* Bp0 = Bt + (size_t)(col0 + r0) * Kd + scch * 8;
    const short* Bp1 = Bt + (size_t)(col0 + r0 + 64) * Kd + scch * 8;

    auto STAGE = [&](int buf, int k0) {
        g2l16(Ap0 + k0, As + buf * 4096 + t * 8);
        g2l16(Ap1 + k0, As + buf * 4096 + 2048 + t * 8);
        g2l16(Bp0 + k0, Bs + buf * 4096 + t * 8);
        g2l16(Bp1 + k0, Bs + buf * 4096 + 2048 + t * 8);
    };

    STAGE(0, 0);
    __syncthreads();

    const int nt = Kd >> 5;
    int cur = 0;
    for (int tt = 0; tt < nt; ++tt) {
        if (tt + 1 < nt) STAGE(cur ^ 1, (tt + 1) * 32);
        const short* Ac = As + cur * 4096;
        const short* Bc = Bs + cur * 4096;
        short8v af[4], bf[4];
#pragma unroll
        for (int m = 0; m < 4; ++m) {
            const int ar = wr * 64 + m * 16 + lrow;
            af[m] = *(const short8v*)(Ac + ar * 32 + ((kc ^ ((ar >> 1) & 3)) * 8));
        }
#pragma unroll
        for (int n = 0; n < 4; ++n) {
            const int br = wc * 64 + n * 16 + lrow;
            bf[n] = *(const short8v*)(Bc + br * 32 + ((kc ^ ((br >> 1) & 3)) * 8));
        }
#pragma unroll
        for (int m = 0; m < 4; ++m)
#pragma unroll
            for (int n = 0; n < 4; ++n)
                acc[m][n] = __builtin_amdgcn_mfma_f32_16x16x32_bf16(
                    af[m], bf[n], acc[m][n], 0, 0, 0);
        __syncthreads();
        cur ^= 1;
    }

    float bcol[4];
#pragma unroll
    for (int n = 0; n < 4; ++n)
        bcol[n] = bias ? bias[col0 + wc * 64 + n * 16 + lrow] : 0.f;

#pragma unroll
    for (int m = 0; m < 4; ++m) {
#pragma unroll
        for (int n = 0; n < 4; ++n) {
            const int col = col0 + wc * 64 + n * 16 + lrow;
#pragma unroll
            for (int r = 0; r < 4; ++r) {
                const int row = row0 + wr * 64 + m * 16 + kc * 4 + r;
                float v = acc[m][n][r] + bcol[n];
                if (ACT == 1) v = 0.5f * v * (1.0f + erff(v * 0.70710678118654752f));
                if (OBF) ((short*)Cout)[(size_t)row * N + col] = f2b(v);
                else     ((float*)Cout)[(size_t)row * N + col] = v;
            }
        }
    }
    (void)M;
}

// ---------------------------------------------------------------- 32-row GEMM (dw)
// 32 rows x 256 cols, K=256, grid M/32 = 512 = 2 blocks/CU (replaces the
// (2,128) 1-block/CU dispatch — the last zero-TLP site). Wave = 16r x 128c.
__global__ __launch_bounds__(256) void mmrow_k(const short* __restrict__ A,
                                               const short* __restrict__ Bt,
                                               short* __restrict__ Cout) {
    __shared__ __align__(16) short As[32 * 32];    // 2 KB
    __shared__ __align__(16) short Bs[256 * 32];   // 16 KB
    const int t = threadIdx.x;
    const int lane = t & 63;
    const int wv = t >> 6;
    const int rg = wv >> 1;          // row group (16 rows)
    const int chl = wv & 1;          // column half (128 cols)
    const int lrow = lane & 15;
    const int kc = lane >> 4;
    const int row0 = blockIdx.x * 32;
    const int Kd = CC;

    f32x4 acc[8];
#pragma unroll
    for (int n = 0; n < 8; ++n) acc[n] = f32x4{0.f, 0.f, 0.f, 0.f};

    const int r0 = t >> 2, cch = t & 3;
    const int scch = cch ^ ((r0 >> 1) & 3);
    const short* Ap  = A  + (size_t)(row0 + (r0 & 31)) * Kd + scch * 8;
    const short* Bq0 = Bt + (size_t)(r0      ) * Kd + scch * 8;
    const short* Bq1 = Bt + (size_t)(r0 +  64) * Kd + scch * 8;
    const short* Bq2 = Bt + (size_t)(r0 + 128) * Kd + scch * 8;
    const short* Bq3 = Bt + (size_t)(r0 + 192) * Kd + scch * 8;

    for (int k0 = 0; k0 < Kd; k0 += 32) {
        __syncthreads();
        if (t < 128) g2l16(Ap + k0, As + t * 8);
        g2l16(Bq0 + k0, Bs + t * 8);
        g2l16(Bq1 + k0, Bs + 2048 + t * 8);
        g2l16(Bq2 + k0, Bs + 4096 + t * 8);
        g2l16(Bq3 + k0, Bs + 6144 + t * 8);
        __syncthreads();
        const int ar = rg * 16 + lrow;
        short8v af = *(const short8v*)(As + ar * 32 + ((kc ^ ((ar >> 1) & 3)) * 8));
#pragma unroll
        for (int n = 0; n < 8; ++n) {
            const int br = chl * 128 + n * 16 + lrow;
            short8v bf = *(const short8v*)(Bs + br * 32 + ((kc ^ ((br >> 1) & 3)) * 8));
            acc[n] = __builtin_amdgcn_mfma_f32_16x16x32_bf16(af, bf, acc[n], 0, 0, 0);
        }
    }

#pragma unroll
    for (int n = 0; n < 8; ++n) {
        const int col = chl * 128 + n * 16 + lrow;
#pragma unroll
        for (int r = 0; r < 4; ++r) {
            const int row = row0 + rg * 16 + kc * 4 + r;
            Cout[(size_t)row * CC + col] = f2b(acc[n][r]);
        }
    }
}

// combined weights, batched: z = (layer<<1)|sel. sel0: WcdT = WatT x Wdst16;
// sel1: Wsv rows [i*512 .. i*512+255] = WatT x Wsrc16.
__global__ __launch_bounds__(256) void wcomb_k(const short* __restrict__ WatT,
                                               const short* __restrict__ Wdst16,
                                               const short* __restrict__ Wsrc16,
                                               short* __restrict__ WcdT,
                                               short* __restrict__ Wsv) {
    __shared__ __align__(16) short As[128 * 32];
    __shared__ __align__(16) short Bs[128 * 32];
    const int z = blockIdx.z, i = z >> 1, sel = z & 1;
    const short* A = WatT + (size_t)i * CC * CC;
    const short* B = (sel ? Wsrc16 : Wdst16) + (size_t)i * CC * CC;
    short* C = sel ? (Wsv + (size_t)i * 2 * CC * CC) : (WcdT + (size_t)i * CC * CC);
    mm_body<0, 1>(As, Bs, A, B, nullptr, C, CC, CC, blockIdx.x, blockIdx.y);
}

// ---------------------------------------------------------------- W2 + residual + LN2 (fused)
// Tile 32 rows x 256 cols, K=1024, grid 512 = 2 blocks/CU. Wave w: rows
// (w>>1)*16..+15, cols (w&1)*128. LN row stats via tiny LDS bounce.
#define W2BM 32
__global__ __launch_bounds__(256) void w2ln_k(
    const short* __restrict__ A,      // h16 [M][1024]
    const short* __restrict__ Bt,     // W2T layer [256][1024]
    const float* __restrict__ bias,
    const float* __restrict__ ln_g, const float* __restrict__ ln_b,
    float* __restrict__ out, short* __restrict__ outb) {
    __shared__ __align__(16) short As[W2BM * 32];     // 2 KB
    __shared__ __align__(16) short Bs[256 * 32];      // 16 KB
    __shared__ float sstat[4][16][2];                 // per-wave row (sum, sumsq)
    const int t = threadIdx.x;
    const int lane = t & 63;
    const int wv = t >> 6;
    const int rg = wv >> 1;
    const int chl = wv & 1;
    const int lrow = lane & 15;
    const int kc = lane >> 4;
    const int row0 = blockIdx.x * W2BM;
    const int Kd = CC * FF;

    f32x4 acc[8];
#pragma unroll
    for (int n = 0; n < 8; ++n) acc[n] = f32x4{0.f, 0.f, 0.f, 0.f};

    const int r0 = t >> 2, cch = t & 3;
    const int scch = cch ^ ((r0 >> 1) & 3);
    const short* Ap  = A  + (size_t)(row0 + (r0 & 31)) * Kd + scch * 8;
    const short* Bq0 = Bt + (size_t)(r0      ) * Kd + scch * 8;
    const short* Bq1 = Bt + (size_t)(r0 +  64) * Kd + scch * 8;
    const short* Bq2 = Bt + (size_t)(r0 + 128) * Kd + scch * 8;
    const short* Bq3 = Bt + (size_t)(r0 + 192) * Kd + scch * 8;

    for (int k0 = 0; k0 < Kd; k0 += 32) {
        __syncthreads();
        if (t < 128) g2l16(Ap + k0, As + t * 8);
        g2l16(Bq0 + k0, Bs + t * 8);
        g2l16(Bq1 + k0, Bs + 2048 + t * 8);
        g2l16(Bq2 + k0, Bs + 4096 + t * 8);
        g2l16(Bq3 + k0, Bs + 6144 + t * 8);
        __syncthreads();
        const int ar = rg * 16 + lrow;
        short8v af = *(const short8v*)(As + ar * 32 + ((kc ^ ((ar >> 1) & 3)) * 8));
#pragma unroll
        for (int n = 0; n < 8; ++n) {
            const int br = chl * 128 + n * 16 + lrow;
            short8v bf = *(const short8v*)(Bs + br * 32 + ((kc ^ ((br >> 1) & 3)) * 8));
            acc[n] = __builtin_amdgcn_mfma_f32_16x16x32_bf16(af, bf, acc[n], 0, 0, 0);
        }
    }

    // pre-LN value: acc += bias + residual(out)
#pragma unroll
    for (int n = 0; n < 8; ++n) {
        const int col = chl * 128 + n * 16 + lrow;
        const float bc = bias[col];
#pragma unroll
        for (int r = 0; r < 4; ++r) {
            const int row = row0 + rg * 16 + kc * 4 + r;
            acc[n][r] += bc + out[(size_t)row * CC + col];
        }
    }
    float psum[4], psq[4];
#pragma unroll
    for (int r = 0; r < 4; ++r) {
        float s = 0.f, q = 0.f;
#pragma unroll
        for (int n = 0; n < 8; ++n) {
            s += acc[n][r];
            q = fmaf(acc[n][r], acc[n][r], q);
        }
        s += __shfl_xor(s, 1); s += __shfl_xor(s, 2);
        s += __shfl_xor(s, 4); s += __shfl_xor(s, 8);
        q += __shfl_xor(q, 1); q += __shfl_xor(q, 2);
        q += __shfl_xor(q, 4); q += __shfl_xor(q, 8);
        psum[r] = s; psq[r] = q;
    }
    if (lrow == 0) {
#pragma unroll
        for (int r = 0; r < 4; ++r) {
            sstat[wv][kc * 4 + r][0] = psum[r];
            sstat[wv][kc * 4 + r][1] = psq[r];
        }
    }
    __syncthreads();
#pragma unroll
    for (int r = 0; r < 4; ++r) {
        const int lr = kc * 4 + r;
        const float s = psum[r] + sstat[wv ^ 1][lr][0];
        const float q = psq[r]  + sstat[wv ^ 1][lr][1];
        const float mu = s * (1.0f / 256.0f);
        const float rstd = rsqrtf(fmaxf(q * (1.0f / 256.0f) - mu * mu, 0.f) + 1e-5f);
        const int row = row0 + rg * 16 + lr;
#pragma unroll
        for (int n = 0; n < 8; ++n) {
            const int col = chl * 128 + n * 16 + lrow;
            const float y = (acc[n][r] - mu) * rstd * ln_g[col] + ln_b[col];
            out[(size_t)row * CC + col] = y;
            outb[(size_t)row * CC + col] = f2b(y);
        }
    }
}

// ---------------------------------------------------------------- attention + residual + LN1 (fused)
// Block = 4 queries x 256 channels; thread handles a CHANNEL PAIR (u32 gather
// = 2 bf16) for 2 queries. swv2 rows are 1024 bf16 (both layers); pointer is
// pre-offset to this layer's 512-bf16 half (stride 512 u32 per row). Softmax
// without max-subtract (relu logits bounded, shift-invariant). Batch<->XCD
// pinning keeps gathers L2-resident.
#define AQB 4
__global__ __launch_bounds__(256) void attn_ln_k(
    const short* __restrict__ dw, const short* __restrict__ swv,
    const int* __restrict__ idx, const float* __restrict__ valid,
    const float* __restrict__ bat,
    const float* __restrict__ ln_g, const float* __restrict__ ln_b,
    float* __restrict__ out, short* __restrict__ outb) {
    __shared__ int   sidx[AQB * KK];
    __shared__ float sval[AQB * KK];
    __shared__ __align__(16) float sconv[AQB][CC];   // 4 KB
    const int t = threadIdx.x;
    const int b   = blockIdx.x & 7;                  // batch, pinned to XCD
    const int blk = blockIdx.x >> 3;                 // 0..511 within batch
    const int bn0 = b * NN + blk * AQB;
    const size_t boff = (size_t)b * LL;              // batch offset into [B*L]

    if (t < AQB * KK) {
        sidx[t] = idx[(size_t)bn0 * KK + t];
        sval[t] = valid[(size_t)bn0 * KK + t];
    }
    __syncthreads();

    const int cp = (t & 127) * 2;                    // channel-pair base
    const int qh = t >> 7;                           // query half: 0 or 1
    const float bias0 = bat[cp], bias1 = bat[cp + 1];
    const unsigned* swvu = (const unsigned*)swv;     // layer-offset; row = 512 u32

#pragma unroll
    for (int qq = 0; qq < 2; ++qq) {
        const int q = qh * 2 + qq;
        const int bn = bn0 + q;
        const unsigned du = *(const unsigned*)(dw + (size_t)bn * CC + cp);
        const float d0 = blo(du) + bias0;
        const float d1 = bhi(du) + bias1;
        float s0 = 0.f, s1 = 0.f, n0 = 0.f, n1 = 0.f;
#pragma unroll
        for (int k = 0; k < KK; ++k) {
            const int j = sidx[q * KK + k];
            const float vv = sval[q * KK + k];
            const unsigned* rp = swvu + (boff + j) * 512;
            const unsigned su = rp[cp >> 1];
            const unsigned vu = rp[128 + (cp >> 1)];
            const float e0 = vv * __expf(fmaxf(d0 - blo(su), 0.f));
            const float e1 = vv * __expf(fmaxf(d1 - bhi(su), 0.f));
            s0 += e0; s1 += e1;
            n0 = fmaf(e0, blo(vu), n0);
            n1 = fmaf(e1, bhi(vu), n1);
        }
        sconv[q][cp]     = (s0 > 0.f) ? n0 / s0 : 0.f;
        sconv[q][cp + 1] = (s1 > 0.f) ? n1 / s1 : 0.f;
    }
    __syncthreads();

    const int lane = t & 63, w = t >> 6;
    float4 gg = *reinterpret_cast<const float4*>(&ln_g[lane * 4]);
    float4 bb = *reinterpret_cast<const float4*>(&ln_b[lane * 4]);
    {
        const int q = w;                             // one query per wave
        const size_t base = (size_t)(bn0 + q) * CC + lane * 4;
        float4 x = *reinterpret_cast<const float4*>(&out[base]);
        float4 d = *reinterpret_cast<const float4*>(&sconv[q][lane * 4]);
        float v0 = x.x + d.x, v1 = x.y + d.y, v2 = x.z + d.z, v3 = x.w + d.w;
        float s = v0 + v1 + v2 + v3;
#pragma unroll
        for (int o = 32; o > 0; o >>= 1) s += __shfl_xor(s, o);
        const float mu = s * (1.0f / 256.0f);
        const float t0 = v0 - mu, t1 = v1 - mu, t2 = v2 - mu, t3 = v3 - mu;
        float qv = t0 * t0 + t1 * t1 + t2 * t2 + t3 * t3;
#pragma unroll
        for (int o = 32; o > 0; o >>= 1) qv += __shfl_xor(qv, o);
        const float rstd = rsqrtf(qv * (1.0f / 256.0f) + 1e-5f);
        float4 y;
        y.x = t0 * rstd * gg.x + bb.x;
        y.y = t1 * rstd * gg.y + bb.y;
        y.z = t2 * rstd * gg.z + bb.z;
        y.w = t3 * rstd * gg.w + bb.w;
        *reinterpret_cast<float4*>(&out[base]) = y;
        short o4[4] = {f2b(y.x), f2b(y.y), f2b(y.z), f2b(y.w)};
        *reinterpret_cast<int2*>(outb + base) = *reinterpret_cast<int2*>(o4);
    }
}

// ---------------------------------------------------------------- launch
extern "C" void kernel_launch(void* const* d_in, const int* in_sizes, int n_in,
                              void* d_out, int out_size, void* d_ws, size_t ws_size,
                              hipStream_t stream) {
    const float* q_xyz   = (const float*)d_in[0];
    const float* q_feat  = (const float*)d_in[1];
    const float* kv_xyz  = (const float*)d_in[2];
    const float* kv_feat = (const float*)d_in[3];
    const float* W_src   = (const float*)d_in[4];
    const float* W_dst   = (const float*)d_in[5];
    const float* W_lin   = (const float*)d_in[6];
    const float* W_attn  = (const float*)d_in[7];
    const float* b_attn  = (const float*)d_in[8];
    const float* W1      = (const float*)d_in[9];
    const float* b1      = (const float*)d_in[10];
    const float* W2      = (const float*)d_in[11];
    const float* b2      = (const float*)d_in[12];
    const float* ln1_g   = (const float*)d_in[13];
    const float* ln1_b   = (const float*)d_in[14];
    const float* ln2_g   = (const float*)d_in[15];
    const float* ln2_b   = (const float*)d_in[16];

    float* out = (float*)d_out;
    char* wsb = (char*)d_ws;
    const size_t MB = (size_t)1 << 20;
    int*   idxb   = (int*)(wsb);                 // 1 MB
    float* validb = (float*)(wsb + 1 * MB);      // 1 MB
    short* kvf16  = (short*)(wsb + 2 * MB);      // 8 MB
    short* outb16 = (short*)(wsb + 10 * MB);     // 8 MB
    short* dw16   = (short*)(wsb + 18 * MB);     // 8 MB
    short* swv2   = (short*)(wsb + 26 * MB);     // 32 MB  [M][1024] (l0 sw|v, l1 sw|v)
    short* h16    = (short*)(wsb + 58 * MB);     // 32 MB
    short* WatT   = (short*)(wsb + 90 * MB);                  // 256 KB
    short* Wdst16 = (short*)(wsb + 90 * MB + 256 * 1024);     // 256 KB
    short* Wsrc16 = (short*)(wsb + 90 * MB + 512 * 1024);     // 256 KB
    short* WcdT   = (short*)(wsb + 90 * MB + 768 * 1024);     // 256 KB
    short* Wsv    = (short*)(wsb + 91 * MB);     // 512 KB  [NL][512][256]
    short* W1T    = (short*)(wsb + 92 * MB);     // 1 MB
    short* W2T    = (short*)(wsb + 93 * MB);     // 1 MB

    const int M = BB * NN;                       // 16384

    init_k<<<M * CC / (256 * 4), 256, 0, stream>>>(q_feat, out, outb16);
    f2b_k<<<M * CC / (256 * 4), 256, 0, stream>>>(kv_feat, kvf16);
    f2b_k<<<NL * CC * CC / (256 * 4), 256, 0, stream>>>(W_dst, Wdst16);
    f2b_k<<<NL * CC * CC / (256 * 4), 256, 0, stream>>>(W_src, Wsrc16);
    knn_k<<<BB * (NN / QPB), 256, 0, stream>>>(q_xyz, kv_xyz, idxb, validb);

    // weight prep (batched over z)
    tconvB_k<<<dim3(8, 8, NL), 256, 0, stream>>>(W_attn, WatT, CC, CC,
                                                 (size_t)CC * CC, (size_t)CC * CC);
    tconvB_k<<<dim3(8, 8, NL), 256, 0, stream>>>(W_lin, Wsv + CC * CC, CC, CC,
                                                 (size_t)CC * CC, (size_t)2 * CC * CC);
    tconvB_k<<<dim3(32, 8, NL), 256, 0, stream>>>(W1, W1T, CC, CC * FF,
                                                  (size_t)CC * CC * FF, (size_t)CC * CC * FF);
    tconvB_k<<<dim3(8, 32, NL), 256, 0, stream>>>(W2, W2T, CC * FF, CC,
                                                  (size_t)CC * CC * FF, (size_t)CC * CC * FF);
    wcomb_k<<<dim3(2, 2, 2 * NL), 256, 0, stream>>>(WatT, Wdst16, Wsrc16, WcdT, Wsv);

    // both layers' sw|v in one GEMM: [M][1024] = kvf16 x Wsv^T (4 blocks/CU)
    mmdb_k<0, 1><<<dim3(8, 128), 256, 0, stream>>>(kvf16, Wsv, nullptr, swv2,
                                                   M, 4 * CC, CC);

    for (int i = 0; i < NL; ++i) {
        const size_t oF = (size_t)i * CC * CC * FF;
        const size_t oC = (size_t)i * CC * CC;
        const float* bat = b_attn + (size_t)i * CC;
        const float* b1p = b1 + (size_t)i * CC * FF;
        const float* b2p = b2 + (size_t)i * CC;

        mmrow_k<<<M / 32, 256, 0, stream>>>(outb16, WcdT + oC, dw16);

        attn_ln_k<<<M / AQB, 256, 0, stream>>>(dw16, swv2 + (size_t)i * 512,
                                               idxb, validb, bat,
                                               ln1_g + (size_t)i * CC, ln1_b + (size_t)i * CC,
                                               out, outb16);

        mmdb_k<1, 1><<<dim3(8, 128), 256, 0, stream>>>(outb16, W1T + oF, b1p, h16,
                                                       M, CC * FF, CC);
        w2ln_k<<<M / W2BM, 256, 0, stream>>>(h16, W2T + oF, b2p,
                                             ln2_g + (size_t)i * CC, ln2_b + (size_t)i * CC,
                                             out, outb16);
    }
    (void)in_sizes; (void)n_in; (void)out_size; (void)ws_size;
}